// Round 14
// baseline (566.921 us; speedup 1.0000x reference)
//
#include <hip/hip_runtime.h>
#include <stdint.h>
#include <stddef.h>

typedef float f32x4 __attribute__((ext_vector_type(4)));
typedef __bf16 bf16x8 __attribute__((ext_vector_type(8)));
typedef short s16x4 __attribute__((ext_vector_type(4)));

#define DEVI static __device__ __forceinline__

DEVI float bf2f(unsigned short u) {
  unsigned int x = ((unsigned int)u) << 16;
  float f;
  __builtin_memcpy(&f, &x, 4);
  return f;
}
DEVI unsigned short f2bf(float f) {
  unsigned int x;
  __builtin_memcpy(&x, &f, 4);
  unsigned int r = (x + 0x7fffu + ((x >> 16) & 1u)) >> 16;
  return (unsigned short)r;
}

DEVI void async16(const void* g, void* l) {
  __builtin_amdgcn_global_load_lds((__attribute__((address_space(1))) void*)g,
                                   (__attribute__((address_space(3))) void*)l,
                                   16, 0, 0);
}

// raw barrier with own-LDS-ops drain; vmcnt NOT touched.
#define BAR_LGKM()                                          \
  do {                                                      \
    asm volatile("s_waitcnt lgkmcnt(0)" ::: "memory");      \
    __builtin_amdgcn_s_barrier();                           \
    __builtin_amdgcn_sched_barrier(0);                      \
  } while (0)

// counted-vmcnt barrier: N loads may stay in flight (T4).
#define BAR_VM(N)                                               \
  do {                                                          \
    asm volatile("s_waitcnt vmcnt(" #N ")" ::: "memory");       \
    __builtin_amdgcn_s_barrier();                               \
    __builtin_amdgcn_sched_barrier(0);                          \
  } while (0)

// ---------------- fp32 -> bf16 conversion ----------------
__global__ __launch_bounds__(256) void cvt_bf16(const float* __restrict__ in,
                                                unsigned short* __restrict__ out, int n) {
  int i = (blockIdx.x * 256 + threadIdx.x) * 4;
  if (i >= n) return;
  float4 v = *(const float4*)(in + i);
  s16x4 o;
  o[0] = (short)f2bf(v.x);
  o[1] = (short)f2bf(v.y);
  o[2] = (short)f2bf(v.z);
  o[3] = (short)f2bf(v.w);
  *(s16x4*)(out + i) = o;
}

// ---------------- RoPE table: tab[t][0..63]=cos, tab[t][64..127]=sin ----------------
__global__ __launch_bounds__(256) void rope_table(float* __restrict__ tab) {
  int idx = blockIdx.x * 256 + threadIdx.x;
  if (idx >= 2048 * 64) return;
  int tt = idx >> 6, j = idx & 63;
  float inv = powf(10000.0f, -(float)j * (1.0f / 64.0f));
  float ang = (float)tt * inv;
  tab[tt * 128 + j] = cosf(ang);
  tab[tt * 128 + 64 + j] = sinf(ang);
}

// ---------------- 256x256 8-phase GEMM; EPI=1 fuses RoPE into the Q/K epilogue ----
// R14: (a) M-fastest XCD chunking: each XCD's 96 consecutive wg = all-M x 3
// N-tiles -> B panel (3MB) L2-resident. (b) EPI=1 Q/K epilogue applies RoPE:
// partner value (d <-> d+64) lives in neighbor wave wc^1 at the SAME
// (mp,nfi,r,g,lr); bounce Q/K acc through the 128KB LDS in pure register order
// (stride-1, conflict-free), combine own fp32 with partner bf16, write the same
// global location. Q additionally scaled by 1/sqrt(hd)*log2(e). V path as before.
// Interior = R12 schedule (best measured): quad order (0,0)->(0,1)->(1,1)->(1,0),
// two persistent B-frag sets, r3/r7 zero-ds_read; vmcnt(2)@r3, vmcnt(4)@r7.
template <int EPI>
__global__ __launch_bounds__(512) void gemm256(const unsigned short* __restrict__ A,
                                               const unsigned short* __restrict__ B,
                                               float* __restrict__ C, int M, int N, int K,
                                               unsigned short* __restrict__ Q,
                                               unsigned short* __restrict__ Kk,
                                               unsigned short* __restrict__ VT,
                                               const float* __restrict__ tab) {
  __shared__ __attribute__((aligned(128))) unsigned short SH[65536];  // 128KB
  const int t = threadIdx.x;
  const int lane = t & 63;
  const int w = t >> 6, wr = w >> 2, wc = w & 3;
  const int g = lane >> 4, lr = lane & 15;

  const int id = blockIdx.y * gridDim.x + blockIdx.x;
  const int nwg = gridDim.x * gridDim.y;
  const int wg = (id & 7) * (nwg >> 3) + (id >> 3);  // XCD-chunked (nwg%8==0)
  const int mt = M >> 8;
  const int bm = (wg % mt) * 256, bn = (wg / mt) * 256;  // M-fastest within chunk

  const unsigned short* aptr = A + (size_t)bm * K;
  const unsigned short* bptr = B + (size_t)bn * K;

  const int srow = t >> 3;                 // 0..63
  const int sslot = (t & 7) ^ (srow & 7);  // inverse-swizzled source 16B slot

#define SHA(p, h) (SH + (p) * 16384 + (h) * 8192)
#define SHB(p, h) (SH + 32768 + (p) * 16384 + (h) * 8192)

#define STG(dstp, mat, h, kt)                                                     \
  do {                                                                            \
    const unsigned short* _s =                                                    \
        (mat) + (size_t)((h) * 128 + srow) * K + (size_t)(kt) * 64 + sslot * 8;   \
    async16(_s, (dstp) + t * 8);                                                  \
    async16(_s + (size_t)64 * K, (dstp) + t * 8 + 4096);                          \
  } while (0)

  const int u0 = ((g ^ (lr & 7)) * 8) + lr * 64;
  const int u1 = (((4 + g) ^ (lr & 7)) * 8) + lr * 64;

#define LDA_(p, mh)                                                               \
  _Pragma("unroll") for (int mf = 0; mf < 4; ++mf) {                              \
    af[mf][0] = *(const bf16x8*)(SHA(p, wr) + (mh) * 4096 + mf * 1024 + u0);      \
    af[mf][1] = *(const bf16x8*)(SHA(p, wr) + (mh) * 4096 + mf * 1024 + u1);      \
  }
#define LDB_(dst, p, nh)                                                          \
  _Pragma("unroll") for (int nf = 0; nf < 2; ++nf) {                              \
    dst[nf][0] = *(const bf16x8*)(SHB(p, wc >> 1) + (wc & 1) * 4096 +             \
                                  (nh) * 2048 + nf * 1024 + u0);                  \
    dst[nf][1] = *(const bf16x8*)(SHB(p, wc >> 1) + (wc & 1) * 4096 +             \
                                  (nh) * 2048 + nf * 1024 + u1);                  \
  }
#define MMA_(bsrc, mh, nh)                                                        \
  __builtin_amdgcn_s_setprio(1);                                                  \
  _Pragma("unroll") for (int mf = 0; mf < 4; ++mf)                                \
      _Pragma("unroll") for (int nf = 0; nf < 2; ++nf) {                          \
    acc[(mh) * 4 + mf][(nh) * 2 + nf] = __builtin_amdgcn_mfma_f32_16x16x32_bf16(  \
        af[mf][0], bsrc[nf][0], acc[(mh) * 4 + mf][(nh) * 2 + nf], 0, 0, 0);      \
    acc[(mh) * 4 + mf][(nh) * 2 + nf] = __builtin_amdgcn_mfma_f32_16x16x32_bf16(  \
        af[mf][1], bsrc[nf][1], acc[(mh) * 4 + mf][(nh) * 2 + nf], 0, 0, 0);      \
  }                                                                               \
  __builtin_amdgcn_s_setprio(0);
#define BARR() __builtin_amdgcn_s_barrier();

  f32x4 acc[8][4] = {};
  bf16x8 af[4][2], bfrA[2][2], bfrB[2][2];

  // prologue: tile0's 4 halves (8 loads, oldest), then t1's B halves (4 loads).
  STG(SHA(0, 0), aptr, 0, 0);
  STG(SHA(0, 1), aptr, 1, 0);
  STG(SHB(0, 0), bptr, 0, 0);
  STG(SHB(0, 1), bptr, 1, 0);
  STG(SHB(1, 0), bptr, 0, 1);
  STG(SHB(1, 1), bptr, 1, 1);
  asm volatile("s_waitcnt vmcnt(4)" ::: "memory");  // tile0's 8 loads landed
  __builtin_amdgcn_s_barrier();

  const int NITER = K >> 7;
  for (int i = 0; i < NITER; ++i) {
    const bool G = (i + 1 < NITER);
    const int t1 = 2 * i + 1, t2 = 2 * i + 2, t3 = 2 * i + 3;

    // r0: tile(p0) quad(mh0,nh0); stage t1's A (free since prev r6)
    LDA_(0, 0);
    LDB_(bfrA, 0, 0);
    STG(SHA(1, 0), aptr, 0, t1);
    STG(SHA(1, 1), aptr, 1, t1);
    BARR();
    MMA_(bfrA, 0, 0);
    BARR();
    // r1: quad(mh0,nh1), A reused in regs
    LDB_(bfrB, 0, 1);
    BARR();
    MMA_(bfrB, 0, 1);
    BARR();
    // r2: quad(mh1,nh1), B(nh1) reused
    LDA_(0, 1);
    BARR();
    MMA_(bfrB, 1, 1);
    BARR();
    // r3: quad(mh1,nh0) — all regs; stage B(0,h0,t2); vmcnt(2) drains t1's 8.
    if (G) {
      STG(SHB(0, 0), bptr, 0, t2);
      asm volatile("s_waitcnt vmcnt(2)" ::: "memory");
    } else {
      asm volatile("s_waitcnt vmcnt(0)" ::: "memory");
    }
    BARR();
    MMA_(bfrA, 1, 0);
    BARR();
    // r4: tile(p1) quad(mh0,nh0); stage B(0,h1,t2)
    LDA_(1, 0);
    LDB_(bfrA, 1, 0);
    if (G) STG(SHB(0, 1), bptr, 1, t2);
    BARR();
    MMA_(bfrA, 0, 0);
    BARR();
    // r5: quad(mh0,nh1); stage A(0,h0,t2)
    LDB_(bfrB, 1, 1);
    if (G) STG(SHA(0, 0), aptr, 0, t2);
    BARR();
    MMA_(bfrB, 0, 1);
    BARR();
    // r6: quad(mh1,nh1); stage A(0,h1,t2)
    LDA_(1, 1);
    if (G) STG(SHA(0, 1), aptr, 1, t2);
    BARR();
    MMA_(bfrB, 1, 1);
    BARR();
    // r7: quad(mh1,nh0) — all regs; stage B(1,both,t3); vmcnt(4) drains t2's 8.
    if (G) {
      STG(SHB(1, 0), bptr, 0, t3);
      STG(SHB(1, 1), bptr, 1, t3);
      asm volatile("s_waitcnt vmcnt(4)" ::: "memory");
    }
    BARR();
    MMA_(bfrA, 1, 0);
    BARR();
  }
#undef STG
#undef LDA_
#undef LDB_
#undef MMA_
#undef BARR

  // epilogue
  if (EPI == 0) {
#pragma unroll
    for (int mp = 0; mp < 8; ++mp) {
      int m0 = bm + wr * 128 + (mp >> 2) * 64 + (mp & 3) * 16 + g * 4;
#pragma unroll
      for (int nfi = 0; nfi < 4; ++nfi) {
        int n = bn + wc * 64 + (nfi >> 1) * 32 + (nfi & 1) * 16 + lr;
#pragma unroll
        for (int r = 0; r < 4; ++r) C[(size_t)(m0 + r) * N + n] = acc[mp][nfi][r];
      }
    }
  } else {
    const int bi = bm >> 11;
    const int tbase = bm & 2047;
    const int region = bn >> 11;  // block-uniform (256-tile within 2048 region)
    if (region == 2) {
      // V: transpose-store, unchanged
#pragma unroll
      for (int nfi = 0; nfi < 4; ++nfi) {
        int e2 = (bn & 2047) + wc * 64 + (nfi >> 1) * 32 + (nfi & 1) * 16 + lr;
        int h = e2 >> 7, d = e2 & 127;
        int bh = bi * 16 + h;
#pragma unroll
        for (int mp = 0; mp < 8; ++mp) {
          int trow = tbase + wr * 128 + (mp >> 2) * 64 + (mp & 3) * 16 + g * 4;
          s16x4 pk;
#pragma unroll
          for (int r = 0; r < 4; ++r) pk[r] = (short)f2bf(acc[mp][nfi][r]);
          *(s16x4*)(VT + ((size_t)bh * 128 + d) * 2048 + trow) = pk;
        }
      }
    } else {
      // Q/K with fused RoPE. Partner (d <-> d^64) is neighbor wave wc^1, same
      // (mp,nfi,r,g,lr). Bounce through LDS in register order (stride-1).
      unsigned short* dst = (region == 0) ? Q : Kk;
      const float scq = (region == 0) ? (0.0883883476483184f * 1.44269504088896341f) : 1.0f;
      __syncthreads();  // all MFMA LDS reads done everywhere
      unsigned short* myb = SH + w * 8192;
#pragma unroll
      for (int mp = 0; mp < 8; ++mp)
#pragma unroll
        for (int nfi = 0; nfi < 4; ++nfi)
#pragma unroll
          for (int r = 0; r < 4; ++r)
            myb[mp * 1024 + nfi * 256 + r * 64 + g * 16 + lr] = f2bf(acc[mp][nfi][r]);
      __syncthreads();
      const unsigned short* pb = SH + (w ^ 1) * 8192;
      const int odd = wc & 1;
#pragma unroll
      for (int nfi = 0; nfi < 4; ++nfi) {
        int j = (nfi >> 1) * 32 + (nfi & 1) * 16 + lr;  // 0..63 within head
        int e2 = (bn & 2047) + wc * 64 + j - odd * 64 + odd * 64;  // = base+wc*64+j
        e2 = (bn & 2047) + wc * 64 + (nfi >> 1) * 32 + (nfi & 1) * 16 + lr;
        int h = e2 >> 7, d = e2 & 127;
        int bh = bi * 16 + h;
#pragma unroll
        for (int mp = 0; mp < 8; ++mp) {
          int tt0 = tbase + wr * 128 + (mp >> 2) * 64 + (mp & 3) * 16 + g * 4;
#pragma unroll
          for (int r = 0; r < 4; ++r) {
            float x1 = acc[mp][nfi][r];
            float x2 = bf2f(pb[mp * 1024 + nfi * 256 + r * 64 + g * 16 + lr]);
            const float* tr = tab + (size_t)(tt0 + r) * 128 + j;
            float cv = tr[0], sv = tr[64];
            float o = odd ? (x2 * sv + x1 * cv) : (x1 * cv - x2 * sv);
            dst[((size_t)bh * 2048 + tt0 + r) * 128 + d] = f2bf(o * scq);
          }
        }
      }
    }
  }
#undef SHA
#undef SHB
}

// ---------------- flash attention (R8, unchanged) ----------------
__global__ __launch_bounds__(256) void flash_attn(const unsigned short* __restrict__ Qg,
                                                  const unsigned short* __restrict__ Kg,
                                                  const unsigned short* __restrict__ VTg,
                                                  unsigned short* __restrict__ Yg,
                                                  const int* __restrict__ iscausal,
                                                  const unsigned char* __restrict__ amask) {
  __shared__ __attribute__((aligned(128))) unsigned short Ks[2][64 * 128];
  __shared__ __attribute__((aligned(128))) unsigned short Vs[2][128 * 64];
  __shared__ __attribute__((aligned(128))) unsigned short Ps[4][16 * 72];

  const int t = threadIdx.x, lane = t & 63, w = t >> 6;
  const int g = lane >> 4, lr = lane & 15;
  const int id = blockIdx.x;
  const int xcd = id & 7, j5 = id >> 3;
  const int bh = xcd * 8 + (j5 >> 5);
  const int qbi = 31 - (j5 & 31);
  const int b = bh >> 4;
  const int qb = qbi * 64;
  const int causal = iscausal[0] != 0;
  const int nt = causal ? (qbi + 1) : 32;

  const unsigned short* qrow = Qg + ((size_t)bh * 2048 + qb + w * 16 + lr) * 128;
  bf16x8 qf[4];
#pragma unroll
  for (int ds = 0; ds < 4; ++ds) qf[ds] = *(const bf16x8*)(qrow + ds * 32 + g * 8);

  const unsigned short* Kbase = Kg + (size_t)bh * 2048 * 128;
  const unsigned short* Vbase = VTg + (size_t)bh * 128 * 2048;

  const int rK = t >> 4, sK = ((t & 15) ^ rK);
  const int rV = t >> 3, sV = ((t & 7) ^ ((t >> 3) & 7));

#define STAGE(KT, P)                                                                    \
  do {                                                                                  \
    const int _kv = (KT) * 64;                                                          \
    _Pragma("unroll") for (int c = 0; c < 4; ++c)                                       \
        async16(Kbase + (size_t)(_kv + c * 16 + rK) * 128 + sK * 8,                     \
                &Ks[P][c * 2048 + t * 8]);                                              \
    _Pragma("unroll") for (int c = 0; c < 4; ++c)                                       \
        async16(Vbase + (size_t)(c * 32 + rV) * 2048 + _kv + sV * 8,                    \
                &Vs[P][c * 2048 + t * 8]);                                              \
  } while (0)

  unsigned int oi[4] = {0x3F803F80u, 0x3F803F80u, 0x3F803F80u, 0x3F803F80u};
  bf16x8 ones;
  __builtin_memcpy(&ones, oi, 16);

  f32x4 acc[8] = {};
  f32x4 accl = {0.f, 0.f, 0.f, 0.f};
  float mrow[4] = {-1e30f, -1e30f, -1e30f, -1e30f};

  STAGE(0, 0);

  for (int kt = 0; kt < nt; ++kt) {
    const int p = kt & 1;
    const int kv0 = kt * 64;
    if (kt + 1 < nt) {
      STAGE(kt + 1, p ^ 1);
      BAR_VM(8);
    } else {
      BAR_VM(0);
    }

    f32x4 s[4] = {};
    __builtin_amdgcn_s_setprio(1);
#pragma unroll
    for (int cf = 0; cf < 4; ++cf)
#pragma unroll
      for (int ds = 0; ds < 4; ++ds) {
        bf16x8 kf = *(const bf16x8*)(&Ks[p][(cf * 16 + lr) * 128 + (((ds * 4 + g) ^ lr) * 8)]);
        s[cf] = __builtin_amdgcn_mfma_f32_16x16x32_bf16(qf[ds], kf, s[cf], 0, 0, 0);
      }
    __builtin_amdgcn_s_setprio(0);

    const int q0 = qb + w * 16 + g * 4;
    if (causal) {
      if (kt == qbi) {
#pragma unroll
        for (int cf = 0; cf < 4; ++cf) {
          int kvg = kv0 + cf * 16 + lr;
#pragma unroll
          for (int r = 0; r < 4; ++r)
            if (kvg > q0 + r) s[cf][r] = -1e30f;
        }
      }
    } else {
#pragma unroll
      for (int cf = 0; cf < 4; ++cf) {
        int kvg = kv0 + cf * 16 + lr;
        if (!amask[(size_t)b * 2048 + kvg]) {
#pragma unroll
          for (int r = 0; r < 4; ++r) s[cf][r] = -1e30f;
        }
      }
    }

    f32x4 lm;
#pragma unroll
    for (int r = 0; r < 4; ++r)
      lm[r] = fmaxf(fmaxf(s[0][r], s[1][r]), fmaxf(s[2][r], s[3][r]));
    bool ok = true;
#pragma unroll
    for (int r = 0; r < 4; ++r) ok = ok && (lm[r] <= mrow[r] + 8.0f);
    if (!__all(ok)) {
      f32x4 mx = lm;
#pragma unroll
      for (int off = 8; off >= 1; off >>= 1)
#pragma unroll
        for (int r = 0; r < 4; ++r) mx[r] = fmaxf(mx[r], __shfl_xor(mx[r], off));
#pragma unroll
      for (int r = 0; r < 4; ++r) {
        float mn = fmaxf(mrow[r], mx[r]);
        float corr = exp2f(mrow[r] - mn);
        mrow[r] = mn;
        accl[r] *= corr;
#pragma unroll
        for (int jf = 0; jf < 8; ++jf) acc[jf][r] *= corr;
      }
    }

#pragma unroll
    for (int cf = 0; cf < 4; ++cf)
#pragma unroll
      for (int r = 0; r < 4; ++r) s[cf][r] = exp2f(s[cf][r] - mrow[r]);

    unsigned short* Pw = &Ps[w][0];
#pragma unroll
    for (int cf = 0; cf < 4; ++cf)
#pragma unroll
      for (int r = 0; r < 4; ++r) Pw[(g * 4 + r) * 72 + cf * 16 + lr] = f2bf(s[cf][r]);
    asm volatile("s_waitcnt lgkmcnt(0)" ::: "memory");
    __builtin_amdgcn_sched_barrier(0);

    bf16x8 pa0 = *(const bf16x8*)(Pw + lr * 72 + g * 8);
    bf16x8 pa1 = *(const bf16x8*)(Pw + lr * 72 + 32 + g * 8);

    accl = __builtin_amdgcn_mfma_f32_16x16x32_bf16(pa0, ones, accl, 0, 0, 0);
    accl = __builtin_amdgcn_mfma_f32_16x16x32_bf16(pa1, ones, accl, 0, 0, 0);

    __builtin_amdgcn_s_setprio(1);
#pragma unroll
    for (int jf = 0; jf < 8; ++jf) {
      bf16x8 v0 = *(const bf16x8*)(&Vs[p][(jf * 16 + lr) * 64 + ((g ^ (lr & 7)) * 8)]);
      bf16x8 v1 = *(const bf16x8*)(&Vs[p][(jf * 16 + lr) * 64 + (((4 + g) ^ (lr & 7)) * 8)]);
      acc[jf] = __builtin_amdgcn_mfma_f32_16x16x32_bf16(pa0, v0, acc[jf], 0, 0, 0);
      acc[jf] = __builtin_amdgcn_mfma_f32_16x16x32_bf16(pa1, v1, acc[jf], 0, 0, 0);
    }
    __builtin_amdgcn_s_setprio(0);

    BAR_LGKM();
  }
#undef STAGE

  const int h = bh & 15;
  float rl[4];
#pragma unroll
  for (int r = 0; r < 4; ++r) rl[r] = __builtin_amdgcn_rcpf(accl[r]);
#pragma unroll
  for (int jf = 0; jf < 8; ++jf)
#pragma unroll
    for (int r = 0; r < 4; ++r) {
      int tt = qb + w * 16 + g * 4 + r;
      Yg[((size_t)b * 2048 + tt) * 2048 + h * 128 + jf * 16 + lr] = f2bf(acc[jf][r] * rl[r]);
    }
}

// ---------------- launch ----------------
extern "C" void kernel_launch(void* const* d_in, const int* in_sizes, int n_in, void* d_out,
                              int out_size, void* d_ws, size_t ws_size, hipStream_t stream) {
  const float* x = (const float*)d_in[0];
  const unsigned char* amask = (const unsigned char*)d_in[1];
  const int* iscausal = (const int*)d_in[2];
  const float* wqkv = (const float*)d_in[3];
  const float* wout = (const float*)d_in[4];
  float* out = (float*)d_out;

  const size_t MT = 8192, D = 2048, ND = 6144;
  unsigned short* xb = (unsigned short*)d_ws;
  unsigned short* wqkvb = xb + MT * D;
  unsigned short* woutb = wqkvb + ND * D;
  unsigned short* q = woutb + D * D;
  unsigned short* k = q + MT * D;
  unsigned short* vt = k + MT * D;
  unsigned short* y = vt + MT * D;
  float* tab = (float*)(y + MT * D);
  if (ws_size < (size_t)(100663296) * 2 + 2048 * 128 * 4) return;

  cvt_bf16<<<dim3(16384), dim3(256), 0, stream>>>(x, xb, (int)(MT * D));
  cvt_bf16<<<dim3(12288), dim3(256), 0, stream>>>(wqkv, wqkvb, (int)(ND * D));
  cvt_bf16<<<dim3(4096), dim3(256), 0, stream>>>(wout, woutb, (int)(D * D));
  rope_table<<<dim3(512), dim3(256), 0, stream>>>(tab);
  gemm256<1><<<dim3(24, 32), dim3(512), 0, stream>>>(xb, wqkvb, nullptr, 8192, 6144, 2048, q, k,
                                                     vt, tab);
  flash_attn<<<dim3(2048), dim3(256), 0, stream>>>(q, k, vt, y, iscausal, amask);
  gemm256<0><<<dim3(8, 32), dim3(512), 0, stream>>>(y, woutb, out, 8192, 2048, 2048, nullptr,
                                                    nullptr, nullptr, nullptr);
}

// Round 15
// 486.211 us; speedup vs baseline: 1.1660x; 1.1660x over previous
//
#include <hip/hip_runtime.h>
#include <stdint.h>
#include <stddef.h>

typedef float f32x4 __attribute__((ext_vector_type(4)));
typedef __bf16 bf16x8 __attribute__((ext_vector_type(8)));
typedef short s16x4 __attribute__((ext_vector_type(4)));

#define DEVI static __device__ __forceinline__

DEVI float bf2f(unsigned short u) {
  unsigned int x = ((unsigned int)u) << 16;
  float f;
  __builtin_memcpy(&f, &x, 4);
  return f;
}
DEVI unsigned short f2bf(float f) {
  unsigned int x;
  __builtin_memcpy(&x, &f, 4);
  unsigned int r = (x + 0x7fffu + ((x >> 16) & 1u)) >> 16;
  return (unsigned short)r;
}

DEVI void async16(const void* g, void* l) {
  __builtin_amdgcn_global_load_lds((__attribute__((address_space(1))) void*)g,
                                   (__attribute__((address_space(3))) void*)l,
                                   16, 0, 0);
}

// raw barrier with own-LDS-ops drain; vmcnt NOT touched.
#define BAR_LGKM()                                          \
  do {                                                      \
    asm volatile("s_waitcnt lgkmcnt(0)" ::: "memory");      \
    __builtin_amdgcn_s_barrier();                           \
    __builtin_amdgcn_sched_barrier(0);                      \
  } while (0)

// counted-vmcnt barrier: N loads may stay in flight (T4).
#define BAR_VM(N)                                               \
  do {                                                          \
    asm volatile("s_waitcnt vmcnt(" #N ")" ::: "memory");       \
    __builtin_amdgcn_s_barrier();                               \
    __builtin_amdgcn_sched_barrier(0);                          \
  } while (0)

// ---------------- fp32 -> bf16 conversion ----------------
__global__ __launch_bounds__(256) void cvt_bf16(const float* __restrict__ in,
                                                unsigned short* __restrict__ out, int n) {
  int i = (blockIdx.x * 256 + threadIdx.x) * 4;
  if (i >= n) return;
  float4 v = *(const float4*)(in + i);
  s16x4 o;
  o[0] = (short)f2bf(v.x);
  o[1] = (short)f2bf(v.y);
  o[2] = (short)f2bf(v.z);
  o[3] = (short)f2bf(v.w);
  *(s16x4*)(out + i) = o;
}

// ---------------- RoPE table: tab[t][0..63]=cos, tab[t][64..127]=sin ----------------
__global__ __launch_bounds__(256) void rope_table(float* __restrict__ tab) {
  int idx = blockIdx.x * 256 + threadIdx.x;
  if (idx >= 2048 * 64) return;
  int tt = idx >> 6, j = idx & 63;
  float inv = powf(10000.0f, -(float)j * (1.0f / 64.0f));
  float ang = (float)tt * inv;
  tab[tt * 128 + j] = cosf(ang);
  tab[tt * 128 + 64 + j] = sinf(ang);
}

// ---------------- RoPE apply, vectorized x4; Q pre-scaled by 1/sqrt(hd)*log2(e) ----
__global__ __launch_bounds__(256) void rope_apply(unsigned short* __restrict__ Qg,
                                                  unsigned short* __restrict__ Kg,
                                                  const float* __restrict__ tab) {
  const float S2 = 0.0883883476483184f * 1.44269504088896341f;
  int idx = blockIdx.x * 256 + threadIdx.x;  // bh*2048*16 + tt*16 + j4
  int j4 = idx & 15;
  int tt = (idx >> 4) & 2047;
  int bh = idx >> 15;
  size_t base = ((size_t)bh * 2048 + tt) * 128;
  f32x4 c4 = *(const f32x4*)(tab + tt * 128 + j4 * 4);
  f32x4 s4 = *(const f32x4*)(tab + tt * 128 + 64 + j4 * 4);
  s16x4 q1 = *(const s16x4*)(Qg + base + j4 * 4);
  s16x4 q2 = *(const s16x4*)(Qg + base + 64 + j4 * 4);
  s16x4 k1 = *(const s16x4*)(Kg + base + j4 * 4);
  s16x4 k2 = *(const s16x4*)(Kg + base + 64 + j4 * 4);
  s16x4 o1, o2, p1, p2;
#pragma unroll
  for (int r = 0; r < 4; ++r) {
    float c = c4[r], s = s4[r];
    float a = bf2f((unsigned short)q1[r]), b2 = bf2f((unsigned short)q2[r]);
    o1[r] = (short)f2bf((a * c - b2 * s) * S2);
    o2[r] = (short)f2bf((a * s + b2 * c) * S2);
    float ka = bf2f((unsigned short)k1[r]), kb = bf2f((unsigned short)k2[r]);
    p1[r] = (short)f2bf(ka * c - kb * s);
    p2[r] = (short)f2bf(ka * s + kb * c);
  }
  *(s16x4*)(Qg + base + j4 * 4) = o1;
  *(s16x4*)(Qg + base + 64 + j4 * 4) = o2;
  *(s16x4*)(Kg + base + j4 * 4) = p1;
  *(s16x4*)(Kg + base + 64 + j4 * 4) = p2;
}

// ---------------- 256x256 8-phase GEMM: C[m][n] = sum_k A[m][k]*B[n][k] ----------------
// R15 = R12 interior (best measured: 237us, 0 conflicts) + balanced rectangular
// XCD chunking: tile grid partitioned into 4x2 rectangles (one per XCD);
// QKV: 8Mx12N tiles -> 8MB A + 12MB B per XCD (was 4+24=28MB); out: 8Mx4N.
// M-fastest within rect so each 32-block round is a compact 8x4 sub-rect.
// Interior: quad order (0,0)->(0,1)->(1,1)->(1,0), two persistent B-frag sets,
// r3/r7 zero-ds_read; vmcnt(2)@r3, vmcnt(4)@r7; phase entry = s_barrier only.
template <int EPI>
__global__ __launch_bounds__(512) void gemm256(const unsigned short* __restrict__ A,
                                               const unsigned short* __restrict__ B,
                                               float* __restrict__ C, int M, int N, int K,
                                               unsigned short* __restrict__ Q,
                                               unsigned short* __restrict__ Kk,
                                               unsigned short* __restrict__ VT) {
  __shared__ __attribute__((aligned(128))) unsigned short Al[2][2][8192];
  __shared__ __attribute__((aligned(128))) unsigned short Bl[2][2][8192];
  const int t = threadIdx.x;
  const int lane = t & 63;
  const int w = t >> 6, wr = w >> 2, wc = w & 3;
  const int g = lane >> 4, lr = lane & 15;

  // balanced rectangular XCD chunking (requires mt%4==0, nt%2==0)
  const int id = blockIdx.y * gridDim.x + blockIdx.x;
  const int mt = M >> 8, nt = N >> 8;
  const int xcd = id & 7;
  const int local = id >> 3;             // 0..(mt*nt/8-1)
  const int rm = mt >> 2, rn = nt >> 1;  // rect = rm x rn tiles
  const int bm = ((xcd & 3) * rm + (local % rm)) * 256;
  const int bn = ((xcd >> 2) * rn + (local / rm)) * 256;

  const unsigned short* aptr = A + (size_t)bm * K;
  const unsigned short* bptr = B + (size_t)bn * K;

  const int srow = t >> 3;                 // 0..63
  const int sslot = (t & 7) ^ (srow & 7);  // inverse-swizzled source 16B slot

#define STG(arr, mat, p, h, kt)                                                   \
  do {                                                                            \
    const unsigned short* _s =                                                    \
        (mat) + (size_t)((h) * 128 + srow) * K + (size_t)(kt) * 64 + sslot * 8;   \
    async16(_s, &arr[p][h][t * 8]);                                               \
    async16(_s + (size_t)64 * K, &arr[p][h][t * 8 + 4096]);                       \
  } while (0)

  const int u0 = ((g ^ (lr & 7)) * 8) + lr * 64;
  const int u1 = (((4 + g) ^ (lr & 7)) * 8) + lr * 64;

#define LDA_(p, mh)                                                               \
  _Pragma("unroll") for (int mf = 0; mf < 4; ++mf) {                              \
    af[mf][0] = *(const bf16x8*)&Al[p][wr][(mh) * 4096 + mf * 1024 + u0];         \
    af[mf][1] = *(const bf16x8*)&Al[p][wr][(mh) * 4096 + mf * 1024 + u1];         \
  }
#define LDB_(dst, p, nh)                                                          \
  _Pragma("unroll") for (int nf = 0; nf < 2; ++nf) {                              \
    dst[nf][0] = *(const bf16x8*)&Bl[p][wc >> 1][(wc & 1) * 4096 + (nh) * 2048 +  \
                                                 nf * 1024 + u0];                 \
    dst[nf][1] = *(const bf16x8*)&Bl[p][wc >> 1][(wc & 1) * 4096 + (nh) * 2048 +  \
                                                 nf * 1024 + u1];                 \
  }
#define MMA_(bsrc, mh, nh)                                                        \
  __builtin_amdgcn_s_setprio(1);                                                  \
  _Pragma("unroll") for (int mf = 0; mf < 4; ++mf)                                \
      _Pragma("unroll") for (int nf = 0; nf < 2; ++nf) {                          \
    acc[(mh) * 4 + mf][(nh) * 2 + nf] = __builtin_amdgcn_mfma_f32_16x16x32_bf16(  \
        af[mf][0], bsrc[nf][0], acc[(mh) * 4 + mf][(nh) * 2 + nf], 0, 0, 0);      \
    acc[(mh) * 4 + mf][(nh) * 2 + nf] = __builtin_amdgcn_mfma_f32_16x16x32_bf16(  \
        af[mf][1], bsrc[nf][1], acc[(mh) * 4 + mf][(nh) * 2 + nf], 0, 0, 0);      \
  }                                                                               \
  __builtin_amdgcn_s_setprio(0);
#define BARR() __builtin_amdgcn_s_barrier();

  f32x4 acc[8][4] = {};
  bf16x8 af[4][2], bfrA[2][2], bfrB[2][2];

  // prologue: tile0's 4 halves (8 loads, oldest), then t1's B halves (4 loads).
  STG(Al, aptr, 0, 0, 0);
  STG(Al, aptr, 0, 1, 0);
  STG(Bl, bptr, 0, 0, 0);
  STG(Bl, bptr, 0, 1, 0);
  STG(Bl, bptr, 1, 0, 1);
  STG(Bl, bptr, 1, 1, 1);
  asm volatile("s_waitcnt vmcnt(4)" ::: "memory");  // tile0's 8 loads landed
  __builtin_amdgcn_s_barrier();

  const int NITER = K >> 7;
  for (int i = 0; i < NITER; ++i) {
    const bool G = (i + 1 < NITER);
    const int t1 = 2 * i + 1, t2 = 2 * i + 2, t3 = 2 * i + 3;

    // r0: tile(p0) quad(mh0,nh0); stage t1's A (Al[1] free since prev r6)
    LDA_(0, 0);
    LDB_(bfrA, 0, 0);
    STG(Al, aptr, 1, 0, t1);
    STG(Al, aptr, 1, 1, t1);
    BARR();
    MMA_(bfrA, 0, 0);
    BARR();
    // r1: quad(mh0,nh1), A reused in regs
    LDB_(bfrB, 0, 1);
    BARR();
    MMA_(bfrB, 0, 1);
    BARR();
    // r2: quad(mh1,nh1), B(nh1) reused in regs
    LDA_(0, 1);
    BARR();
    MMA_(bfrB, 1, 1);
    BARR();
    // r3: quad(mh1,nh0) — all from regs; stage B(0,h0,t2) (Bl[0] free after r1);
    // vmcnt(2): drains prev-r7's B(t1) 4 + r0's A(t1) 4 before r4 reads them.
    if (G) {
      STG(Bl, bptr, 0, 0, t2);
      asm volatile("s_waitcnt vmcnt(2)" ::: "memory");
    } else {
      asm volatile("s_waitcnt vmcnt(0)" ::: "memory");
    }
    BARR();
    MMA_(bfrA, 1, 0);
    BARR();
    // r4: tile(p1) quad(mh0,nh0); stage B(0,h1,t2)
    LDA_(1, 0);
    LDB_(bfrA, 1, 0);
    if (G) STG(Bl, bptr, 0, 1, t2);
    BARR();
    MMA_(bfrA, 0, 0);
    BARR();
    // r5: quad(mh0,nh1); stage A(0,h0,t2) (Al[0] free after r2)
    LDB_(bfrB, 1, 1);
    if (G) STG(Al, aptr, 0, 0, t2);
    BARR();
    MMA_(bfrB, 0, 1);
    BARR();
    // r6: quad(mh1,nh1); stage A(0,h1,t2)
    LDA_(1, 1);
    if (G) STG(Al, aptr, 0, 1, t2);
    BARR();
    MMA_(bfrB, 1, 1);
    BARR();
    // r7: quad(mh1,nh0) — all from regs; stage B(1,both,t3) (Bl[1] free after r5);
    // vmcnt(4): drains t2's 8 loads before next r0 reads them.
    if (G) {
      STG(Bl, bptr, 1, 0, t3);
      STG(Bl, bptr, 1, 1, t3);
      asm volatile("s_waitcnt vmcnt(4)" ::: "memory");
    }
    BARR();
    MMA_(bfrA, 1, 0);
    BARR();
  }
#undef STG
#undef LDA_
#undef LDB_
#undef MMA_
#undef BARR

  // epilogue: acc[mh*4+mf][nh*2+nf]: row off = (mp>>2)*64+(mp&3)*16+g*4,
  // col off = (nfi>>1)*32 + (nfi&1)*16 + lr.
  if (EPI == 0) {
#pragma unroll
    for (int mp = 0; mp < 8; ++mp) {
      int m0 = bm + wr * 128 + (mp >> 2) * 64 + (mp & 3) * 16 + g * 4;
#pragma unroll
      for (int nfi = 0; nfi < 4; ++nfi) {
        int n = bn + wc * 64 + (nfi >> 1) * 32 + (nfi & 1) * 16 + lr;
#pragma unroll
        for (int r = 0; r < 4; ++r) C[(size_t)(m0 + r) * N + n] = acc[mp][nfi][r];
      }
    }
  } else {
    const int bi = bm >> 11;
    const int tbase = bm & 2047;
#pragma unroll
    for (int nfi = 0; nfi < 4; ++nfi) {
      int e = bn + wc * 64 + (nfi >> 1) * 32 + (nfi & 1) * 16 + lr;  // region uniform/block
      int region = e >> 11;
      int e2 = e & 2047;
      int h = e2 >> 7, d = e2 & 127;
      int bh = bi * 16 + h;
#pragma unroll
      for (int mp = 0; mp < 8; ++mp) {
        int trow = tbase + wr * 128 + (mp >> 2) * 64 + (mp & 3) * 16 + g * 4;
        if (region == 2) {
          s16x4 pk;
#pragma unroll
          for (int r = 0; r < 4; ++r) pk[r] = (short)f2bf(acc[mp][nfi][r]);
          *(s16x4*)(VT + ((size_t)bh * 128 + d) * 2048 + trow) = pk;
        } else {
          unsigned short* dst = (region == 0) ? Q : Kk;
#pragma unroll
          for (int r = 0; r < 4; ++r)
            dst[((size_t)bh * 2048 + trow + r) * 128 + d] = f2bf(acc[mp][nfi][r]);
        }
      }
    }
  }
}

// ---------------- flash attention (R8, unchanged) ----------------
__global__ __launch_bounds__(256) void flash_attn(const unsigned short* __restrict__ Qg,
                                                  const unsigned short* __restrict__ Kg,
                                                  const unsigned short* __restrict__ VTg,
                                                  unsigned short* __restrict__ Yg,
                                                  const int* __restrict__ iscausal,
                                                  const unsigned char* __restrict__ amask) {
  __shared__ __attribute__((aligned(128))) unsigned short Ks[2][64 * 128];
  __shared__ __attribute__((aligned(128))) unsigned short Vs[2][128 * 64];
  __shared__ __attribute__((aligned(128))) unsigned short Ps[4][16 * 72];

  const int t = threadIdx.x, lane = t & 63, w = t >> 6;
  const int g = lane >> 4, lr = lane & 15;
  const int id = blockIdx.x;
  const int xcd = id & 7, j5 = id >> 3;
  const int bh = xcd * 8 + (j5 >> 5);
  const int qbi = 31 - (j5 & 31);
  const int b = bh >> 4;
  const int qb = qbi * 64;
  const int causal = iscausal[0] != 0;
  const int nt = causal ? (qbi + 1) : 32;

  const unsigned short* qrow = Qg + ((size_t)bh * 2048 + qb + w * 16 + lr) * 128;
  bf16x8 qf[4];
#pragma unroll
  for (int ds = 0; ds < 4; ++ds) qf[ds] = *(const bf16x8*)(qrow + ds * 32 + g * 8);

  const unsigned short* Kbase = Kg + (size_t)bh * 2048 * 128;
  const unsigned short* Vbase = VTg + (size_t)bh * 128 * 2048;

  const int rK = t >> 4, sK = ((t & 15) ^ rK);
  const int rV = t >> 3, sV = ((t & 7) ^ ((t >> 3) & 7));

#define STAGE(KT, P)                                                                    \
  do {                                                                                  \
    const int _kv = (KT) * 64;                                                          \
    _Pragma("unroll") for (int c = 0; c < 4; ++c)                                       \
        async16(Kbase + (size_t)(_kv + c * 16 + rK) * 128 + sK * 8,                     \
                &Ks[P][c * 2048 + t * 8]);                                              \
    _Pragma("unroll") for (int c = 0; c < 4; ++c)                                       \
        async16(Vbase + (size_t)(c * 32 + rV) * 2048 + _kv + sV * 8,                    \
                &Vs[P][c * 2048 + t * 8]);                                              \
  } while (0)

  unsigned int oi[4] = {0x3F803F80u, 0x3F803F80u, 0x3F803F80u, 0x3F803F80u};
  bf16x8 ones;
  __builtin_memcpy(&ones, oi, 16);

  f32x4 acc[8] = {};
  f32x4 accl = {0.f, 0.f, 0.f, 0.f};
  float mrow[4] = {-1e30f, -1e30f, -1e30f, -1e30f};

  STAGE(0, 0);

  for (int kt = 0; kt < nt; ++kt) {
    const int p = kt & 1;
    const int kv0 = kt * 64;
    if (kt + 1 < nt) {
      STAGE(kt + 1, p ^ 1);
      BAR_VM(8);
    } else {
      BAR_VM(0);
    }

    f32x4 s[4] = {};
    __builtin_amdgcn_s_setprio(1);
#pragma unroll
    for (int cf = 0; cf < 4; ++cf)
#pragma unroll
      for (int ds = 0; ds < 4; ++ds) {
        bf16x8 kf = *(const bf16x8*)(&Ks[p][(cf * 16 + lr) * 128 + (((ds * 4 + g) ^ lr) * 8)]);
        s[cf] = __builtin_amdgcn_mfma_f32_16x16x32_bf16(qf[ds], kf, s[cf], 0, 0, 0);
      }
    __builtin_amdgcn_s_setprio(0);

    const int q0 = qb + w * 16 + g * 4;
    if (causal) {
      if (kt == qbi) {
#pragma unroll
        for (int cf = 0; cf < 4; ++cf) {
          int kvg = kv0 + cf * 16 + lr;
#pragma unroll
          for (int r = 0; r < 4; ++r)
            if (kvg > q0 + r) s[cf][r] = -1e30f;
        }
      }
    } else {
#pragma unroll
      for (int cf = 0; cf < 4; ++cf) {
        int kvg = kv0 + cf * 16 + lr;
        if (!amask[(size_t)b * 2048 + kvg]) {
#pragma unroll
          for (int r = 0; r < 4; ++r) s[cf][r] = -1e30f;
        }
      }
    }

    f32x4 lm;
#pragma unroll
    for (int r = 0; r < 4; ++r)
      lm[r] = fmaxf(fmaxf(s[0][r], s[1][r]), fmaxf(s[2][r], s[3][r]));
    bool ok = true;
#pragma unroll
    for (int r = 0; r < 4; ++r) ok = ok && (lm[r] <= mrow[r] + 8.0f);
    if (!__all(ok)) {
      f32x4 mx = lm;
#pragma unroll
      for (int off = 8; off >= 1; off >>= 1)
#pragma unroll
        for (int r = 0; r < 4; ++r) mx[r] = fmaxf(mx[r], __shfl_xor(mx[r], off));
#pragma unroll
      for (int r = 0; r < 4; ++r) {
        float mn = fmaxf(mrow[r], mx[r]);
        float corr = exp2f(mrow[r] - mn);
        mrow[r] = mn;
        accl[r] *= corr;
#pragma unroll
        for (int jf = 0; jf < 8; ++jf) acc[jf][r] *= corr;
      }
    }

#pragma unroll
    for (int cf = 0; cf < 4; ++cf)
#pragma unroll
      for (int r = 0; r < 4; ++r) s[cf][r] = exp2f(s[cf][r] - mrow[r]);

    unsigned short* Pw = &Ps[w][0];
#pragma unroll
    for (int cf = 0; cf < 4; ++cf)
#pragma unroll
      for (int r = 0; r < 4; ++r) Pw[(g * 4 + r) * 72 + cf * 16 + lr] = f2bf(s[cf][r]);
    asm volatile("s_waitcnt lgkmcnt(0)" ::: "memory");
    __builtin_amdgcn_sched_barrier(0);

    bf16x8 pa0 = *(const bf16x8*)(Pw + lr * 72 + g * 8);
    bf16x8 pa1 = *(const bf16x8*)(Pw + lr * 72 + 32 + g * 8);

    accl = __builtin_amdgcn_mfma_f32_16x16x32_bf16(pa0, ones, accl, 0, 0, 0);
    accl = __builtin_amdgcn_mfma_f32_16x16x32_bf16(pa1, ones, accl, 0, 0, 0);

    __builtin_amdgcn_s_setprio(1);
#pragma unroll
    for (int jf = 0; jf < 8; ++jf) {
      bf16x8 v0 = *(const bf16x8*)(&Vs[p][(jf * 16 + lr) * 64 + ((g ^ (lr & 7)) * 8)]);
      bf16x8 v1 = *(const bf16x8*)(&Vs[p][(jf * 16 + lr) * 64 + (((4 + g) ^ (lr & 7)) * 8)]);
      acc[jf] = __builtin_amdgcn_mfma_f32_16x16x32_bf16(pa0, v0, acc[jf], 0, 0, 0);
      acc[jf] = __builtin_amdgcn_mfma_f32_16x16x32_bf16(pa1, v1, acc[jf], 0, 0, 0);
    }
    __builtin_amdgcn_s_setprio(0);

    BAR_LGKM();
  }
#undef STAGE

  const int h = bh & 15;
  float rl[4];
#pragma unroll
  for (int r = 0; r < 4; ++r) rl[r] = __builtin_amdgcn_rcpf(accl[r]);
#pragma unroll
  for (int jf = 0; jf < 8; ++jf)
#pragma unroll
    for (int r = 0; r < 4; ++r) {
      int tt = qb + w * 16 + g * 4 + r;
      Yg[((size_t)b * 2048 + tt) * 2048 + h * 128 + jf * 16 + lr] = f2bf(acc[jf][r] * rl[r]);
    }
}

// ---------------- launch ----------------
extern "C" void kernel_launch(void* const* d_in, const int* in_sizes, int n_in, void* d_out,
                              int out_size, void* d_ws, size_t ws_size, hipStream_t stream) {
  const float* x = (const float*)d_in[0];
  const unsigned char* amask = (const unsigned char*)d_in[1];
  const int* iscausal = (const int*)d_in[2];
  const float* wqkv = (const float*)d_in[3];
  const float* wout = (const float*)d_in[4];
  float* out = (float*)d_out;

  const size_t MT = 8192, D = 2048, ND = 6144;
  unsigned short* xb = (unsigned short*)d_ws;
  unsigned short* wqkvb = xb + MT * D;
  unsigned short* woutb = wqkvb + ND * D;
  unsigned short* q = woutb + D * D;
  unsigned short* k = q + MT * D;
  unsigned short* vt = k + MT * D;
  unsigned short* y = vt + MT * D;
  float* tab = (float*)(y + MT * D);
  if (ws_size < (size_t)(100663296) * 2 + 2048 * 128 * 4) return;

  cvt_bf16<<<dim3(16384), dim3(256), 0, stream>>>(x, xb, (int)(MT * D));
  cvt_bf16<<<dim3(12288), dim3(256), 0, stream>>>(wqkv, wqkvb, (int)(ND * D));
  cvt_bf16<<<dim3(4096), dim3(256), 0, stream>>>(wout, woutb, (int)(D * D));
  rope_table<<<dim3(512), dim3(256), 0, stream>>>(tab);
  gemm256<1><<<dim3(24, 32), dim3(512), 0, stream>>>(xb, wqkvb, nullptr, 8192, 6144, 2048, q, k, vt);
  rope_apply<<<dim3(8192), dim3(256), 0, stream>>>(q, k, tab);
  flash_attn<<<dim3(2048), dim3(256), 0, stream>>>(q, k, vt, y, iscausal, amask);
  gemm256<0><<<dim3(8, 32), dim3(512), 0, stream>>>(y, woutb, out, 8192, 2048, 2048, nullptr,
                                                    nullptr, nullptr);
}

// Round 16
// 465.796 us; speedup vs baseline: 1.2171x; 1.0438x over previous
//
#include <hip/hip_runtime.h>
#include <stdint.h>
#include <stddef.h>

typedef float f32x4 __attribute__((ext_vector_type(4)));
typedef __bf16 bf16x8 __attribute__((ext_vector_type(8)));
typedef short s16x4 __attribute__((ext_vector_type(4)));

#define DEVI static __device__ __forceinline__

DEVI float bf2f(unsigned short u) {
  unsigned int x = ((unsigned int)u) << 16;
  float f;
  __builtin_memcpy(&f, &x, 4);
  return f;
}
DEVI unsigned short f2bf(float f) {
  unsigned int x;
  __builtin_memcpy(&x, &f, 4);
  unsigned int r = (x + 0x7fffu + ((x >> 16) & 1u)) >> 16;
  return (unsigned short)r;
}

DEVI void async16(const void* g, void* l) {
  __builtin_amdgcn_global_load_lds((__attribute__((address_space(1))) void*)g,
                                   (__attribute__((address_space(3))) void*)l,
                                   16, 0, 0);
}

// counted-vmcnt barrier: N loads may stay in flight (T4).
#define BAR_VM(N)                                               \
  do {                                                          \
    asm volatile("s_waitcnt vmcnt(" #N ")" ::: "memory");       \
    __builtin_amdgcn_s_barrier();                               \
    __builtin_amdgcn_sched_barrier(0);                          \
  } while (0)

// raw barrier with own-LDS-ops drain; vmcnt NOT touched.
#define BAR_LGKM()                                          \
  do {                                                      \
    asm volatile("s_waitcnt lgkmcnt(0)" ::: "memory");      \
    __builtin_amdgcn_s_barrier();                           \
    __builtin_amdgcn_sched_barrier(0);                      \
  } while (0)

// ---------------- fused fp32 -> bf16 conversion for x, w_qkv, w_out ----------------
__global__ __launch_bounds__(256) void cvt3(const float* __restrict__ x,
                                            const float* __restrict__ wq,
                                            const float* __restrict__ wo,
                                            unsigned short* __restrict__ xb,
                                            unsigned short* __restrict__ wqb,
                                            unsigned short* __restrict__ wob) {
  const int n1 = 16777216, n2 = 12582912;
  int i = (blockIdx.x * 256 + threadIdx.x) * 4;
  const float* src;
  unsigned short* dst;
  int off;
  if (i < n1) {
    src = x; dst = xb; off = i;
  } else if (i < n1 + n2) {
    src = wq; dst = wqb; off = i - n1;
  } else {
    src = wo; dst = wob; off = i - n1 - n2;
  }
  float4 v = *(const float4*)(src + off);
  s16x4 o;
  o[0] = (short)f2bf(v.x);
  o[1] = (short)f2bf(v.y);
  o[2] = (short)f2bf(v.z);
  o[3] = (short)f2bf(v.w);
  *(s16x4*)(dst + off) = o;
}

// ---------------- RoPE table: tab[t][0..63]=cos, tab[t][64..127]=sin ----------------
__global__ __launch_bounds__(256) void rope_table(float* __restrict__ tab) {
  int idx = blockIdx.x * 256 + threadIdx.x;
  if (idx >= 2048 * 64) return;
  int tt = idx >> 6, j = idx & 63;
  float inv = powf(10000.0f, -(float)j * (1.0f / 64.0f));
  float ang = (float)tt * inv;
  tab[tt * 128 + j] = cosf(ang);
  tab[tt * 128 + 64 + j] = sinf(ang);
}

// ---------------- RoPE apply, vectorized x4; Q pre-scaled by 1/sqrt(hd)*log2(e) ----
__global__ __launch_bounds__(256) void rope_apply(unsigned short* __restrict__ Qg,
                                                  unsigned short* __restrict__ Kg,
                                                  const float* __restrict__ tab) {
  const float S2 = 0.0883883476483184f * 1.44269504088896341f;
  int idx = blockIdx.x * 256 + threadIdx.x;  // bh*2048*16 + tt*16 + j4
  int j4 = idx & 15;
  int tt = (idx >> 4) & 2047;
  int bh = idx >> 15;
  size_t base = ((size_t)bh * 2048 + tt) * 128;
  f32x4 c4 = *(const f32x4*)(tab + tt * 128 + j4 * 4);
  f32x4 s4 = *(const f32x4*)(tab + tt * 128 + 64 + j4 * 4);
  s16x4 q1 = *(const s16x4*)(Qg + base + j4 * 4);
  s16x4 q2 = *(const s16x4*)(Qg + base + 64 + j4 * 4);
  s16x4 k1 = *(const s16x4*)(Kg + base + j4 * 4);
  s16x4 k2 = *(const s16x4*)(Kg + base + 64 + j4 * 4);
  s16x4 o1, o2, p1, p2;
#pragma unroll
  for (int r = 0; r < 4; ++r) {
    float c = c4[r], s = s4[r];
    float a = bf2f((unsigned short)q1[r]), b2 = bf2f((unsigned short)q2[r]);
    o1[r] = (short)f2bf((a * c - b2 * s) * S2);
    o2[r] = (short)f2bf((a * s + b2 * c) * S2);
    float ka = bf2f((unsigned short)k1[r]), kb = bf2f((unsigned short)k2[r]);
    p1[r] = (short)f2bf(ka * c - kb * s);
    p2[r] = (short)f2bf(ka * s + kb * c);
  }
  *(s16x4*)(Qg + base + j4 * 4) = o1;
  *(s16x4*)(Qg + base + 64 + j4 * 4) = o2;
  *(s16x4*)(Kg + base + j4 * 4) = p1;
  *(s16x4*)(Kg + base + 64 + j4 * 4) = p2;
}

// ---------------- 256x256 8-phase GEMM (R15: best measured + rect XCD chunk) ----------
template <int EPI>
__global__ __launch_bounds__(512) void gemm256(const unsigned short* __restrict__ A,
                                               const unsigned short* __restrict__ B,
                                               float* __restrict__ C, int M, int N, int K,
                                               unsigned short* __restrict__ Q,
                                               unsigned short* __restrict__ Kk,
                                               unsigned short* __restrict__ VT) {
  __shared__ __attribute__((aligned(128))) unsigned short Al[2][2][8192];
  __shared__ __attribute__((aligned(128))) unsigned short Bl[2][2][8192];
  const int t = threadIdx.x;
  const int lane = t & 63;
  const int w = t >> 6, wr = w >> 2, wc = w & 3;
  const int g = lane >> 4, lr = lane & 15;

  // balanced rectangular XCD chunking (requires mt%4==0, nt%2==0)
  const int id = blockIdx.y * gridDim.x + blockIdx.x;
  const int mt = M >> 8, nt = N >> 8;
  const int xcd = id & 7;
  const int local = id >> 3;
  const int rm = mt >> 2, rn = nt >> 1;
  const int bm = ((xcd & 3) * rm + (local % rm)) * 256;
  const int bn = ((xcd >> 2) * rn + (local / rm)) * 256;

  const unsigned short* aptr = A + (size_t)bm * K;
  const unsigned short* bptr = B + (size_t)bn * K;

  const int srow = t >> 3;
  const int sslot = (t & 7) ^ (srow & 7);

#define STG(arr, mat, p, h, kt)                                                   \
  do {                                                                            \
    const unsigned short* _s =                                                    \
        (mat) + (size_t)((h) * 128 + srow) * K + (size_t)(kt) * 64 + sslot * 8;   \
    async16(_s, &arr[p][h][t * 8]);                                               \
    async16(_s + (size_t)64 * K, &arr[p][h][t * 8 + 4096]);                       \
  } while (0)

  const int u0 = ((g ^ (lr & 7)) * 8) + lr * 64;
  const int u1 = (((4 + g) ^ (lr & 7)) * 8) + lr * 64;

#define LDA_(p, mh)                                                               \
  _Pragma("unroll") for (int mf = 0; mf < 4; ++mf) {                              \
    af[mf][0] = *(const bf16x8*)&Al[p][wr][(mh) * 4096 + mf * 1024 + u0];         \
    af[mf][1] = *(const bf16x8*)&Al[p][wr][(mh) * 4096 + mf * 1024 + u1];         \
  }
#define LDB_(dst, p, nh)                                                          \
  _Pragma("unroll") for (int nf = 0; nf < 2; ++nf) {                              \
    dst[nf][0] = *(const bf16x8*)&Bl[p][wc >> 1][(wc & 1) * 4096 + (nh) * 2048 +  \
                                                 nf * 1024 + u0];                 \
    dst[nf][1] = *(const bf16x8*)&Bl[p][wc >> 1][(wc & 1) * 4096 + (nh) * 2048 +  \
                                                 nf * 1024 + u1];                 \
  }
#define MMA_(bsrc, mh, nh)                                                        \
  __builtin_amdgcn_s_setprio(1);                                                  \
  _Pragma("unroll") for (int mf = 0; mf < 4; ++mf)                                \
      _Pragma("unroll") for (int nf = 0; nf < 2; ++nf) {                          \
    acc[(mh) * 4 + mf][(nh) * 2 + nf] = __builtin_amdgcn_mfma_f32_16x16x32_bf16(  \
        af[mf][0], bsrc[nf][0], acc[(mh) * 4 + mf][(nh) * 2 + nf], 0, 0, 0);      \
    acc[(mh) * 4 + mf][(nh) * 2 + nf] = __builtin_amdgcn_mfma_f32_16x16x32_bf16(  \
        af[mf][1], bsrc[nf][1], acc[(mh) * 4 + mf][(nh) * 2 + nf], 0, 0, 0);      \
  }                                                                               \
  __builtin_amdgcn_s_setprio(0);
#define BARR() __builtin_amdgcn_s_barrier();

  f32x4 acc[8][4] = {};
  bf16x8 af[4][2], bfrA[2][2], bfrB[2][2];

  STG(Al, aptr, 0, 0, 0);
  STG(Al, aptr, 0, 1, 0);
  STG(Bl, bptr, 0, 0, 0);
  STG(Bl, bptr, 0, 1, 0);
  STG(Bl, bptr, 1, 0, 1);
  STG(Bl, bptr, 1, 1, 1);
  asm volatile("s_waitcnt vmcnt(4)" ::: "memory");
  __builtin_amdgcn_s_barrier();

  const int NITER = K >> 7;
  for (int i = 0; i < NITER; ++i) {
    const bool G = (i + 1 < NITER);
    const int t1 = 2 * i + 1, t2 = 2 * i + 2, t3 = 2 * i + 3;

    LDA_(0, 0);
    LDB_(bfrA, 0, 0);
    STG(Al, aptr, 1, 0, t1);
    STG(Al, aptr, 1, 1, t1);
    BARR();
    MMA_(bfrA, 0, 0);
    BARR();
    LDB_(bfrB, 0, 1);
    BARR();
    MMA_(bfrB, 0, 1);
    BARR();
    LDA_(0, 1);
    BARR();
    MMA_(bfrB, 1, 1);
    BARR();
    if (G) {
      STG(Bl, bptr, 0, 0, t2);
      asm volatile("s_waitcnt vmcnt(2)" ::: "memory");
    } else {
      asm volatile("s_waitcnt vmcnt(0)" ::: "memory");
    }
    BARR();
    MMA_(bfrA, 1, 0);
    BARR();
    LDA_(1, 0);
    LDB_(bfrA, 1, 0);
    if (G) STG(Bl, bptr, 0, 1, t2);
    BARR();
    MMA_(bfrA, 0, 0);
    BARR();
    LDB_(bfrB, 1, 1);
    if (G) STG(Al, aptr, 0, 0, t2);
    BARR();
    MMA_(bfrB, 0, 1);
    BARR();
    LDA_(1, 1);
    if (G) STG(Al, aptr, 0, 1, t2);
    BARR();
    MMA_(bfrB, 1, 1);
    BARR();
    if (G) {
      STG(Bl, bptr, 1, 0, t3);
      STG(Bl, bptr, 1, 1, t3);
      asm volatile("s_waitcnt vmcnt(4)" ::: "memory");
    }
    BARR();
    MMA_(bfrA, 1, 0);
    BARR();
  }
#undef STG
#undef LDA_
#undef LDB_
#undef MMA_
#undef BARR

  if (EPI == 0) {
#pragma unroll
    for (int mp = 0; mp < 8; ++mp) {
      int m0 = bm + wr * 128 + (mp >> 2) * 64 + (mp & 3) * 16 + g * 4;
#pragma unroll
      for (int nfi = 0; nfi < 4; ++nfi) {
        int n = bn + wc * 64 + (nfi >> 1) * 32 + (nfi & 1) * 16 + lr;
#pragma unroll
        for (int r = 0; r < 4; ++r) C[(size_t)(m0 + r) * N + n] = acc[mp][nfi][r];
      }
    }
  } else {
    const int bi = bm >> 11;
    const int tbase = bm & 2047;
#pragma unroll
    for (int nfi = 0; nfi < 4; ++nfi) {
      int e = bn + wc * 64 + (nfi >> 1) * 32 + (nfi & 1) * 16 + lr;
      int region = e >> 11;
      int e2 = e & 2047;
      int h = e2 >> 7, d = e2 & 127;
      int bh = bi * 16 + h;
#pragma unroll
      for (int mp = 0; mp < 8; ++mp) {
        int trow = tbase + wr * 128 + (mp >> 2) * 64 + (mp & 3) * 16 + g * 4;
        if (region == 2) {
          s16x4 pk;
#pragma unroll
          for (int r = 0; r < 4; ++r) pk[r] = (short)f2bf(acc[mp][nfi][r]);
          *(s16x4*)(VT + ((size_t)bh * 128 + d) * 2048 + trow) = pk;
        } else {
          unsigned short* dst = (region == 0) ? Q : Kk;
#pragma unroll
          for (int r = 0; r < 4; ++r)
            dst[((size_t)bh * 2048 + trow + r) * 128 + d] = f2bf(acc[mp][nfi][r]);
        }
      }
    }
  }
}

// ---------------- flash attention: QBLK=128, 512 thr = 8 waves ----------------
// R16: halve tile-iterations by doubling q-rows per block. Per-wave structure
// identical to R8 (wave w owns q rows [qb+16w,+16)); K/V LDS layouts and read
// swizzles byte-identical; only the staging thread-map changes (512 threads,
// 4 async16/thread, vmcnt(4) counted barrier). LDS 82KB -> 1 blk/CU = 8 waves
// (same TLP as R8's 2x4). Balanced LPT: qbi permutation makes each CU's 4
// blocks sum to exactly 68 tiles; heavy-first. Causal nt=2qbi+2, per-wave
// mask gate kv0+63>qw (waves 0-3 waste the last tile: ~3%, correct).
__global__ __launch_bounds__(512) void flash_attn(const unsigned short* __restrict__ Qg,
                                                  const unsigned short* __restrict__ Kg,
                                                  const unsigned short* __restrict__ VTg,
                                                  unsigned short* __restrict__ Yg,
                                                  const int* __restrict__ iscausal,
                                                  const unsigned char* __restrict__ amask) {
  __shared__ __attribute__((aligned(128))) unsigned short Ks[2][64 * 128];
  __shared__ __attribute__((aligned(128))) unsigned short Vs[2][128 * 64];
  __shared__ __attribute__((aligned(128))) unsigned short Ps[8][16 * 72];

  const int t = threadIdx.x, lane = t & 63, w = t >> 6;  // w 0..7
  const int g = lane >> 4, lr = lane & 15;
  const int id = blockIdx.x;
  const int xcd = id & 7, j5 = id >> 3;  // j5 0..127
  const int rr = j5 >> 3;                // round 0..15
  // balanced-LPT qbi permutation: rounds {0-3,4-7,8-11,12-15} -> {15-rr, rr-4, 19-rr, rr-8}
  const int qbi = (rr < 4) ? (15 - rr) : (rr < 8) ? (rr - 4) : (rr < 12) ? (19 - rr) : (rr - 8);
  const int bh = xcd * 8 + (j5 & 7);
  const int b = bh >> 4;
  const int qb = qbi * 128;
  const int causal = iscausal[0] != 0;
  const int nt = causal ? (2 * qbi + 2) : 32;

  const unsigned short* qrow = Qg + ((size_t)bh * 2048 + qb + w * 16 + lr) * 128;
  bf16x8 qf[4];
#pragma unroll
  for (int ds = 0; ds < 4; ++ds) qf[ds] = *(const bf16x8*)(qrow + ds * 32 + g * 8);

  const unsigned short* Kbase = Kg + (size_t)bh * 2048 * 128;
  const unsigned short* Vbase = VTg + (size_t)bh * 128 * 2048;

  // staging map (512 thr): K rows rK=t>>4 (chunks of 32), V rows rV=t>>3 (chunks of 64)
  const int rK = t >> 4, sK = (t & 15) ^ (rK & 15);
  const int rV = t >> 3, sV = (t & 7) ^ (rV & 7);

#define STAGE(KT, P)                                                                    \
  do {                                                                                  \
    const int _kv = (KT) * 64;                                                          \
    _Pragma("unroll") for (int c = 0; c < 2; ++c)                                       \
        async16(Kbase + (size_t)(_kv + c * 32 + rK) * 128 + sK * 8,                     \
                &Ks[P][c * 4096 + t * 8]);                                              \
    _Pragma("unroll") for (int c = 0; c < 2; ++c)                                       \
        async16(Vbase + (size_t)(c * 64 + rV) * 2048 + _kv + sV * 8,                    \
                &Vs[P][c * 4096 + t * 8]);                                              \
  } while (0)

  unsigned int oi[4] = {0x3F803F80u, 0x3F803F80u, 0x3F803F80u, 0x3F803F80u};
  bf16x8 ones;
  __builtin_memcpy(&ones, oi, 16);

  f32x4 acc[8] = {};
  f32x4 accl = {0.f, 0.f, 0.f, 0.f};
  float mrow[4] = {-1e30f, -1e30f, -1e30f, -1e30f};

  STAGE(0, 0);

  for (int kt = 0; kt < nt; ++kt) {
    const int p = kt & 1;
    const int kv0 = kt * 64;
    if (kt + 1 < nt) {
      STAGE(kt + 1, p ^ 1);
      BAR_VM(4);
    } else {
      BAR_VM(0);
    }

    f32x4 s[4] = {};
    __builtin_amdgcn_s_setprio(1);
#pragma unroll
    for (int cf = 0; cf < 4; ++cf)
#pragma unroll
      for (int ds = 0; ds < 4; ++ds) {
        bf16x8 kf = *(const bf16x8*)(&Ks[p][(cf * 16 + lr) * 128 + (((ds * 4 + g) ^ lr) * 8)]);
        s[cf] = __builtin_amdgcn_mfma_f32_16x16x32_bf16(qf[ds], kf, s[cf], 0, 0, 0);
      }
    __builtin_amdgcn_s_setprio(0);

    const int qw = qb + w * 16;
    const int q0 = qw + g * 4;
    if (causal) {
      if (kv0 + 63 > qw) {
#pragma unroll
        for (int cf = 0; cf < 4; ++cf) {
          int kvg = kv0 + cf * 16 + lr;
#pragma unroll
          for (int r = 0; r < 4; ++r)
            if (kvg > q0 + r) s[cf][r] = -1e30f;
        }
      }
    } else {
#pragma unroll
      for (int cf = 0; cf < 4; ++cf) {
        int kvg = kv0 + cf * 16 + lr;
        if (!amask[(size_t)b * 2048 + kvg]) {
#pragma unroll
          for (int r = 0; r < 4; ++r) s[cf][r] = -1e30f;
        }
      }
    }

    f32x4 lm;
#pragma unroll
    for (int r = 0; r < 4; ++r)
      lm[r] = fmaxf(fmaxf(s[0][r], s[1][r]), fmaxf(s[2][r], s[3][r]));
    bool ok = true;
#pragma unroll
    for (int r = 0; r < 4; ++r) ok = ok && (lm[r] <= mrow[r] + 8.0f);
    if (!__all(ok)) {
      f32x4 mx = lm;
#pragma unroll
      for (int off = 8; off >= 1; off >>= 1)
#pragma unroll
        for (int r = 0; r < 4; ++r) mx[r] = fmaxf(mx[r], __shfl_xor(mx[r], off));
#pragma unroll
      for (int r = 0; r < 4; ++r) {
        float mn = fmaxf(mrow[r], mx[r]);
        float corr = exp2f(mrow[r] - mn);
        mrow[r] = mn;
        accl[r] *= corr;
#pragma unroll
        for (int jf = 0; jf < 8; ++jf) acc[jf][r] *= corr;
      }
    }

#pragma unroll
    for (int cf = 0; cf < 4; ++cf)
#pragma unroll
      for (int r = 0; r < 4; ++r) s[cf][r] = exp2f(s[cf][r] - mrow[r]);

    unsigned short* Pw = &Ps[w][0];
#pragma unroll
    for (int cf = 0; cf < 4; ++cf)
#pragma unroll
      for (int r = 0; r < 4; ++r) Pw[(g * 4 + r) * 72 + cf * 16 + lr] = f2bf(s[cf][r]);
    asm volatile("s_waitcnt lgkmcnt(0)" ::: "memory");
    __builtin_amdgcn_sched_barrier(0);

    bf16x8 pa0 = *(const bf16x8*)(Pw + lr * 72 + g * 8);
    bf16x8 pa1 = *(const bf16x8*)(Pw + lr * 72 + 32 + g * 8);

    accl = __builtin_amdgcn_mfma_f32_16x16x32_bf16(pa0, ones, accl, 0, 0, 0);
    accl = __builtin_amdgcn_mfma_f32_16x16x32_bf16(pa1, ones, accl, 0, 0, 0);

    __builtin_amdgcn_s_setprio(1);
#pragma unroll
    for (int jf = 0; jf < 8; ++jf) {
      bf16x8 v0 = *(const bf16x8*)(&Vs[p][(jf * 16 + lr) * 64 + ((g ^ (lr & 7)) * 8)]);
      bf16x8 v1 = *(const bf16x8*)(&Vs[p][(jf * 16 + lr) * 64 + (((4 + g) ^ (lr & 7)) * 8)]);
      acc[jf] = __builtin_amdgcn_mfma_f32_16x16x32_bf16(pa0, v0, acc[jf], 0, 0, 0);
      acc[jf] = __builtin_amdgcn_mfma_f32_16x16x32_bf16(pa1, v1, acc[jf], 0, 0, 0);
    }
    __builtin_amdgcn_s_setprio(0);

    BAR_LGKM();
  }
#undef STAGE

  const int h = bh & 15;
  float rl[4];
#pragma unroll
  for (int r = 0; r < 4; ++r) rl[r] = __builtin_amdgcn_rcpf(accl[r]);
#pragma unroll
  for (int jf = 0; jf < 8; ++jf)
#pragma unroll
    for (int r = 0; r < 4; ++r) {
      int tt = qb + w * 16 + g * 4 + r;
      Yg[((size_t)b * 2048 + tt) * 2048 + h * 128 + jf * 16 + lr] = f2bf(acc[jf][r] * rl[r]);
    }
}

// ---------------- launch ----------------
extern "C" void kernel_launch(void* const* d_in, const int* in_sizes, int n_in, void* d_out,
                              int out_size, void* d_ws, size_t ws_size, hipStream_t stream) {
  const float* x = (const float*)d_in[0];
  const unsigned char* amask = (const unsigned char*)d_in[1];
  const int* iscausal = (const int*)d_in[2];
  const float* wqkv = (const float*)d_in[3];
  const float* wout = (const float*)d_in[4];
  float* out = (float*)d_out;

  const size_t MT = 8192, D = 2048, ND = 6144;
  unsigned short* xb = (unsigned short*)d_ws;
  unsigned short* wqkvb = xb + MT * D;
  unsigned short* woutb = wqkvb + ND * D;
  unsigned short* q = woutb + D * D;
  unsigned short* k = q + MT * D;
  unsigned short* vt = k + MT * D;
  unsigned short* y = vt + MT * D;
  float* tab = (float*)(y + MT * D);
  if (ws_size < (size_t)(100663296) * 2 + 2048 * 128 * 4) return;

  cvt3<<<dim3(32768), dim3(256), 0, stream>>>(x, wqkv, wout, xb, wqkvb, woutb);
  rope_table<<<dim3(512), dim3(256), 0, stream>>>(tab);
  gemm256<1><<<dim3(24, 32), dim3(512), 0, stream>>>(xb, wqkvb, nullptr, 8192, 6144, 2048, q, k, vt);
  rope_apply<<<dim3(8192), dim3(256), 0, stream>>>(q, k, tab);
  flash_attn<<<dim3(1024), dim3(512), 0, stream>>>(q, k, vt, y, iscausal, amask);
  gemm256<0><<<dim3(8, 32), dim3(512), 0, stream>>>(y, woutb, out, 8192, 2048, 2048, nullptr,
                                                    nullptr, nullptr);
}

// Round 17
// 441.952 us; speedup vs baseline: 1.2828x; 1.0540x over previous
//
#include <hip/hip_runtime.h>
#include <stdint.h>
#include <stddef.h>

typedef float f32x4 __attribute__((ext_vector_type(4)));
typedef __bf16 bf16x8 __attribute__((ext_vector_type(8)));
typedef short s16x4 __attribute__((ext_vector_type(4)));

#define DEVI static __device__ __forceinline__

DEVI float bf2f(unsigned short u) {
  unsigned int x = ((unsigned int)u) << 16;
  float f;
  __builtin_memcpy(&f, &x, 4);
  return f;
}
DEVI unsigned short f2bf(float f) {
  unsigned int x;
  __builtin_memcpy(&x, &f, 4);
  unsigned int r = (x + 0x7fffu + ((x >> 16) & 1u)) >> 16;
  return (unsigned short)r;
}

DEVI void async16(const void* g, void* l) {
  __builtin_amdgcn_global_load_lds((__attribute__((address_space(1))) void*)g,
                                   (__attribute__((address_space(3))) void*)l,
                                   16, 0, 0);
}

// counted-vmcnt barrier: N loads may stay in flight (T4).
#define BAR_VM(N)                                               \
  do {                                                          \
    asm volatile("s_waitcnt vmcnt(" #N ")" ::: "memory");       \
    __builtin_amdgcn_s_barrier();                               \
    __builtin_amdgcn_sched_barrier(0);                          \
  } while (0)

// raw barrier with own-LDS-ops drain; vmcnt NOT touched.
#define BAR_LGKM()                                          \
  do {                                                      \
    asm volatile("s_waitcnt lgkmcnt(0)" ::: "memory");      \
    __builtin_amdgcn_s_barrier();                           \
    __builtin_amdgcn_sched_barrier(0);                      \
  } while (0)

// ---------------- fused fp32 -> bf16 conversion for x, w_qkv, w_out ----------------
__global__ __launch_bounds__(256) void cvt3(const float* __restrict__ x,
                                            const float* __restrict__ wq,
                                            const float* __restrict__ wo,
                                            unsigned short* __restrict__ xb,
                                            unsigned short* __restrict__ wqb,
                                            unsigned short* __restrict__ wob) {
  const int n1 = 16777216, n2 = 12582912;
  int i = (blockIdx.x * 256 + threadIdx.x) * 4;
  const float* src;
  unsigned short* dst;
  int off;
  if (i < n1) {
    src = x; dst = xb; off = i;
  } else if (i < n1 + n2) {
    src = wq; dst = wqb; off = i - n1;
  } else {
    src = wo; dst = wob; off = i - n1 - n2;
  }
  float4 v = *(const float4*)(src + off);
  s16x4 o;
  o[0] = (short)f2bf(v.x);
  o[1] = (short)f2bf(v.y);
  o[2] = (short)f2bf(v.z);
  o[3] = (short)f2bf(v.w);
  *(s16x4*)(dst + off) = o;
}

// ---------------- RoPE table: tab[t][0..63]=cos, tab[t][64..127]=sin ----------------
__global__ __launch_bounds__(256) void rope_table(float* __restrict__ tab) {
  int idx = blockIdx.x * 256 + threadIdx.x;
  if (idx >= 2048 * 64) return;
  int tt = idx >> 6, j = idx & 63;
  float inv = powf(10000.0f, -(float)j * (1.0f / 64.0f));
  float ang = (float)tt * inv;
  tab[tt * 128 + j] = cosf(ang);
  tab[tt * 128 + 64 + j] = sinf(ang);
}

// ---------------- RoPE apply, vectorized x4; Q pre-scaled by 1/sqrt(hd)*log2(e) ----
__global__ __launch_bounds__(256) void rope_apply(unsigned short* __restrict__ Qg,
                                                  unsigned short* __restrict__ Kg,
                                                  const float* __restrict__ tab) {
  const float S2 = 0.0883883476483184f * 1.44269504088896341f;
  int idx = blockIdx.x * 256 + threadIdx.x;  // bh*2048*16 + tt*16 + j4
  int j4 = idx & 15;
  int tt = (idx >> 4) & 2047;
  int bh = idx >> 15;
  size_t base = ((size_t)bh * 2048 + tt) * 128;
  f32x4 c4 = *(const f32x4*)(tab + tt * 128 + j4 * 4);
  f32x4 s4 = *(const f32x4*)(tab + tt * 128 + 64 + j4 * 4);
  s16x4 q1 = *(const s16x4*)(Qg + base + j4 * 4);
  s16x4 q2 = *(const s16x4*)(Qg + base + 64 + j4 * 4);
  s16x4 k1 = *(const s16x4*)(Kg + base + j4 * 4);
  s16x4 k2 = *(const s16x4*)(Kg + base + 64 + j4 * 4);
  s16x4 o1, o2, p1, p2;
#pragma unroll
  for (int r = 0; r < 4; ++r) {
    float c = c4[r], s = s4[r];
    float a = bf2f((unsigned short)q1[r]), b2 = bf2f((unsigned short)q2[r]);
    o1[r] = (short)f2bf((a * c - b2 * s) * S2);
    o2[r] = (short)f2bf((a * s + b2 * c) * S2);
    float ka = bf2f((unsigned short)k1[r]), kb = bf2f((unsigned short)k2[r]);
    p1[r] = (short)f2bf(ka * c - kb * s);
    p2[r] = (short)f2bf(ka * s + kb * c);
  }
  *(s16x4*)(Qg + base + j4 * 4) = o1;
  *(s16x4*)(Qg + base + 64 + j4 * 4) = o2;
  *(s16x4*)(Kg + base + j4 * 4) = p1;
  *(s16x4*)(Kg + base + 64 + j4 * 4) = p2;
}

// ---------------- 256x256 8-phase GEMM (R15: best measured + rect XCD chunk) ----------
template <int EPI>
__global__ __launch_bounds__(512) void gemm256(const unsigned short* __restrict__ A,
                                               const unsigned short* __restrict__ B,
                                               float* __restrict__ C, int M, int N, int K,
                                               unsigned short* __restrict__ Q,
                                               unsigned short* __restrict__ Kk,
                                               unsigned short* __restrict__ VT) {
  __shared__ __attribute__((aligned(128))) unsigned short Al[2][2][8192];
  __shared__ __attribute__((aligned(128))) unsigned short Bl[2][2][8192];
  const int t = threadIdx.x;
  const int lane = t & 63;
  const int w = t >> 6, wr = w >> 2, wc = w & 3;
  const int g = lane >> 4, lr = lane & 15;

  // balanced rectangular XCD chunking (requires mt%4==0, nt%2==0)
  const int id = blockIdx.y * gridDim.x + blockIdx.x;
  const int mt = M >> 8, nt = N >> 8;
  const int xcd = id & 7;
  const int local = id >> 3;
  const int rm = mt >> 2, rn = nt >> 1;
  const int bm = ((xcd & 3) * rm + (local % rm)) * 256;
  const int bn = ((xcd >> 2) * rn + (local / rm)) * 256;

  const unsigned short* aptr = A + (size_t)bm * K;
  const unsigned short* bptr = B + (size_t)bn * K;

  const int srow = t >> 3;
  const int sslot = (t & 7) ^ (srow & 7);

#define STG(arr, mat, p, h, kt)                                                   \
  do {                                                                            \
    const unsigned short* _s =                                                    \
        (mat) + (size_t)((h) * 128 + srow) * K + (size_t)(kt) * 64 + sslot * 8;   \
    async16(_s, &arr[p][h][t * 8]);                                               \
    async16(_s + (size_t)64 * K, &arr[p][h][t * 8 + 4096]);                       \
  } while (0)

  const int u0 = ((g ^ (lr & 7)) * 8) + lr * 64;
  const int u1 = (((4 + g) ^ (lr & 7)) * 8) + lr * 64;

#define LDA_(p, mh)                                                               \
  _Pragma("unroll") for (int mf = 0; mf < 4; ++mf) {                              \
    af[mf][0] = *(const bf16x8*)&Al[p][wr][(mh) * 4096 + mf * 1024 + u0];         \
    af[mf][1] = *(const bf16x8*)&Al[p][wr][(mh) * 4096 + mf * 1024 + u1];         \
  }
#define LDB_(dst, p, nh)                                                          \
  _Pragma("unroll") for (int nf = 0; nf < 2; ++nf) {                              \
    dst[nf][0] = *(const bf16x8*)&Bl[p][wc >> 1][(wc & 1) * 4096 + (nh) * 2048 +  \
                                                 nf * 1024 + u0];                 \
    dst[nf][1] = *(const bf16x8*)&Bl[p][wc >> 1][(wc & 1) * 4096 + (nh) * 2048 +  \
                                                 nf * 1024 + u1];                 \
  }
#define MMA_(bsrc, mh, nh)                                                        \
  __builtin_amdgcn_s_setprio(1);                                                  \
  _Pragma("unroll") for (int mf = 0; mf < 4; ++mf)                                \
      _Pragma("unroll") for (int nf = 0; nf < 2; ++nf) {                          \
    acc[(mh) * 4 + mf][(nh) * 2 + nf] = __builtin_amdgcn_mfma_f32_16x16x32_bf16(  \
        af[mf][0], bsrc[nf][0], acc[(mh) * 4 + mf][(nh) * 2 + nf], 0, 0, 0);      \
    acc[(mh) * 4 + mf][(nh) * 2 + nf] = __builtin_amdgcn_mfma_f32_16x16x32_bf16(  \
        af[mf][1], bsrc[nf][1], acc[(mh) * 4 + mf][(nh) * 2 + nf], 0, 0, 0);      \
  }                                                                               \
  __builtin_amdgcn_s_setprio(0);
#define BARR() __builtin_amdgcn_s_barrier();

  f32x4 acc[8][4] = {};
  bf16x8 af[4][2], bfrA[2][2], bfrB[2][2];

  STG(Al, aptr, 0, 0, 0);
  STG(Al, aptr, 0, 1, 0);
  STG(Bl, bptr, 0, 0, 0);
  STG(Bl, bptr, 0, 1, 0);
  STG(Bl, bptr, 1, 0, 1);
  STG(Bl, bptr, 1, 1, 1);
  asm volatile("s_waitcnt vmcnt(4)" ::: "memory");
  __builtin_amdgcn_s_barrier();

  const int NITER = K >> 7;
  for (int i = 0; i < NITER; ++i) {
    const bool G = (i + 1 < NITER);
    const int t1 = 2 * i + 1, t2 = 2 * i + 2, t3 = 2 * i + 3;

    LDA_(0, 0);
    LDB_(bfrA, 0, 0);
    STG(Al, aptr, 1, 0, t1);
    STG(Al, aptr, 1, 1, t1);
    BARR();
    MMA_(bfrA, 0, 0);
    BARR();
    LDB_(bfrB, 0, 1);
    BARR();
    MMA_(bfrB, 0, 1);
    BARR();
    LDA_(0, 1);
    BARR();
    MMA_(bfrB, 1, 1);
    BARR();
    if (G) {
      STG(Bl, bptr, 0, 0, t2);
      asm volatile("s_waitcnt vmcnt(2)" ::: "memory");
    } else {
      asm volatile("s_waitcnt vmcnt(0)" ::: "memory");
    }
    BARR();
    MMA_(bfrA, 1, 0);
    BARR();
    LDA_(1, 0);
    LDB_(bfrA, 1, 0);
    if (G) STG(Bl, bptr, 0, 1, t2);
    BARR();
    MMA_(bfrA, 0, 0);
    BARR();
    LDB_(bfrB, 1, 1);
    if (G) STG(Al, aptr, 0, 0, t2);
    BARR();
    MMA_(bfrB, 0, 1);
    BARR();
    LDA_(1, 1);
    if (G) STG(Al, aptr, 0, 1, t2);
    BARR();
    MMA_(bfrB, 1, 1);
    BARR();
    if (G) {
      STG(Bl, bptr, 1, 0, t3);
      STG(Bl, bptr, 1, 1, t3);
      asm volatile("s_waitcnt vmcnt(4)" ::: "memory");
    }
    BARR();
    MMA_(bfrA, 1, 0);
    BARR();
  }
#undef STG
#undef LDA_
#undef LDB_
#undef MMA_
#undef BARR

  if (EPI == 0) {
#pragma unroll
    for (int mp = 0; mp < 8; ++mp) {
      int m0 = bm + wr * 128 + (mp >> 2) * 64 + (mp & 3) * 16 + g * 4;
#pragma unroll
      for (int nfi = 0; nfi < 4; ++nfi) {
        int n = bn + wc * 64 + (nfi >> 1) * 32 + (nfi & 1) * 16 + lr;
#pragma unroll
        for (int r = 0; r < 4; ++r) C[(size_t)(m0 + r) * N + n] = acc[mp][nfi][r];
      }
    }
  } else {
    const int bi = bm >> 11;
    const int tbase = bm & 2047;
#pragma unroll
    for (int nfi = 0; nfi < 4; ++nfi) {
      int e = bn + wc * 64 + (nfi >> 1) * 32 + (nfi & 1) * 16 + lr;
      int region = e >> 11;
      int e2 = e & 2047;
      int h = e2 >> 7, d = e2 & 127;
      int bh = bi * 16 + h;
#pragma unroll
      for (int mp = 0; mp < 8; ++mp) {
        int trow = tbase + wr * 128 + (mp >> 2) * 64 + (mp & 3) * 16 + g * 4;
        if (region == 2) {
          s16x4 pk;
#pragma unroll
          for (int r = 0; r < 4; ++r) pk[r] = (short)f2bf(acc[mp][nfi][r]);
          *(s16x4*)(VT + ((size_t)bh * 128 + d) * 2048 + trow) = pk;
        } else {
          unsigned short* dst = (region == 0) ? Q : Kk;
#pragma unroll
          for (int r = 0; r < 4; ++r)
            dst[((size_t)bh * 2048 + trow + r) * 128 + d] = f2bf(acc[mp][nfi][r]);
        }
      }
    }
  }
}

// ---------------- flash attention: QBLK=256, 1024 thr = 16 waves ----------------
// R17: double QBLK again (R16's verified lever). 16 waves/CU (2x R16's TLP),
// half the tile-iterations; per-wave structure identical. Staging: 1024 thr x
// 16B = exactly one 16KB tile per matrix -> 1 async16/thread each, vmcnt(2).
// Same XOR maps (K: unit^(row&15), V: unit^(row&7)) as verified in R8/R16.
// Compute-skip: causal waves fully masked for a tile skip QK->PV (wave-uniform
// branch; barriers outside) -> tail waste ~0. LPT: qbi = rr&1 ? rr>>1 : 7-(rr>>1).
// LDS 100.4KB -> 1 blk/CU.
__global__ __launch_bounds__(1024) void flash_attn(const unsigned short* __restrict__ Qg,
                                                   const unsigned short* __restrict__ Kg,
                                                   const unsigned short* __restrict__ VTg,
                                                   unsigned short* __restrict__ Yg,
                                                   const int* __restrict__ iscausal,
                                                   const unsigned char* __restrict__ amask) {
  __shared__ __attribute__((aligned(128))) unsigned short Ks[2][64 * 128];
  __shared__ __attribute__((aligned(128))) unsigned short Vs[2][128 * 64];
  __shared__ __attribute__((aligned(128))) unsigned short Ps[16][16 * 72];

  const int t = threadIdx.x, lane = t & 63, w = t >> 6;  // w 0..15
  const int g = lane >> 4, lr = lane & 15;
  const int id = blockIdx.x;
  const int xcd = id & 7, j5 = id >> 3;  // j5 0..63
  const int rr = j5 >> 3;                // round 0..7
  const int qbi = (rr & 1) ? (rr >> 1) : (7 - (rr >> 1));  // {7,0,6,1,5,2,4,3}
  const int bh = xcd * 8 + (j5 & 7);
  const int b = bh >> 4;
  const int qb = qbi * 256;
  const int causal = iscausal[0] != 0;
  const int nt = causal ? (4 * qbi + 4) : 32;

  const unsigned short* qrow = Qg + ((size_t)bh * 2048 + qb + w * 16 + lr) * 128;
  bf16x8 qf[4];
#pragma unroll
  for (int ds = 0; ds < 4; ++ds) qf[ds] = *(const bf16x8*)(qrow + ds * 32 + g * 8);

  const unsigned short* Kbase = Kg + (size_t)bh * 2048 * 128;
  const unsigned short* Vbase = VTg + (size_t)bh * 128 * 2048;

  // staging (1024 thr, 1 load each per matrix): K row rK=t>>4, V row rV=t>>3
  const int rK = t >> 4, sK = (t & 15) ^ (rK & 15);
  const int rV = t >> 3, sV = (t & 7) ^ (rV & 7);

#define STAGE(KT, P)                                                              \
  do {                                                                            \
    const int _kv = (KT) * 64;                                                    \
    async16(Kbase + (size_t)(_kv + rK) * 128 + sK * 8, &Ks[P][t * 8]);            \
    async16(Vbase + (size_t)rV * 2048 + _kv + sV * 8, &Vs[P][t * 8]);             \
  } while (0)

  unsigned int oi[4] = {0x3F803F80u, 0x3F803F80u, 0x3F803F80u, 0x3F803F80u};
  bf16x8 ones;
  __builtin_memcpy(&ones, oi, 16);

  f32x4 acc[8] = {};
  f32x4 accl = {0.f, 0.f, 0.f, 0.f};
  float mrow[4] = {-1e30f, -1e30f, -1e30f, -1e30f};

  STAGE(0, 0);

  for (int kt = 0; kt < nt; ++kt) {
    const int p = kt & 1;
    const int kv0 = kt * 64;
    if (kt + 1 < nt) {
      STAGE(kt + 1, p ^ 1);
      BAR_VM(2);
    } else {
      BAR_VM(0);
    }

    const int qw = qb + w * 16;
    const bool active = !causal || (kv0 <= qw + 15);  // wave-uniform
    if (active) {
      f32x4 s[4] = {};
      __builtin_amdgcn_s_setprio(1);
#pragma unroll
      for (int cf = 0; cf < 4; ++cf)
#pragma unroll
        for (int ds = 0; ds < 4; ++ds) {
          bf16x8 kf = *(const bf16x8*)(&Ks[p][(cf * 16 + lr) * 128 + (((ds * 4 + g) ^ lr) * 8)]);
          s[cf] = __builtin_amdgcn_mfma_f32_16x16x32_bf16(qf[ds], kf, s[cf], 0, 0, 0);
        }
      __builtin_amdgcn_s_setprio(0);

      const int q0 = qw + g * 4;
      if (causal) {
        if (kv0 + 63 > qw) {
#pragma unroll
          for (int cf = 0; cf < 4; ++cf) {
            int kvg = kv0 + cf * 16 + lr;
#pragma unroll
            for (int r = 0; r < 4; ++r)
              if (kvg > q0 + r) s[cf][r] = -1e30f;
          }
        }
      } else {
#pragma unroll
        for (int cf = 0; cf < 4; ++cf) {
          int kvg = kv0 + cf * 16 + lr;
          if (!amask[(size_t)b * 2048 + kvg]) {
#pragma unroll
            for (int r = 0; r < 4; ++r) s[cf][r] = -1e30f;
          }
        }
      }

      f32x4 lm;
#pragma unroll
      for (int r = 0; r < 4; ++r)
        lm[r] = fmaxf(fmaxf(s[0][r], s[1][r]), fmaxf(s[2][r], s[3][r]));
      bool ok = true;
#pragma unroll
      for (int r = 0; r < 4; ++r) ok = ok && (lm[r] <= mrow[r] + 8.0f);
      if (!__all(ok)) {
        f32x4 mx = lm;
#pragma unroll
        for (int off = 8; off >= 1; off >>= 1)
#pragma unroll
          for (int r = 0; r < 4; ++r) mx[r] = fmaxf(mx[r], __shfl_xor(mx[r], off));
#pragma unroll
        for (int r = 0; r < 4; ++r) {
          float mn = fmaxf(mrow[r], mx[r]);
          float corr = exp2f(mrow[r] - mn);
          mrow[r] = mn;
          accl[r] *= corr;
#pragma unroll
          for (int jf = 0; jf < 8; ++jf) acc[jf][r] *= corr;
        }
      }

#pragma unroll
      for (int cf = 0; cf < 4; ++cf)
#pragma unroll
        for (int r = 0; r < 4; ++r) s[cf][r] = exp2f(s[cf][r] - mrow[r]);

      unsigned short* Pw = &Ps[w][0];
#pragma unroll
      for (int cf = 0; cf < 4; ++cf)
#pragma unroll
        for (int r = 0; r < 4; ++r) Pw[(g * 4 + r) * 72 + cf * 16 + lr] = f2bf(s[cf][r]);
      asm volatile("s_waitcnt lgkmcnt(0)" ::: "memory");
      __builtin_amdgcn_sched_barrier(0);

      bf16x8 pa0 = *(const bf16x8*)(Pw + lr * 72 + g * 8);
      bf16x8 pa1 = *(const bf16x8*)(Pw + lr * 72 + 32 + g * 8);

      accl = __builtin_amdgcn_mfma_f32_16x16x32_bf16(pa0, ones, accl, 0, 0, 0);
      accl = __builtin_amdgcn_mfma_f32_16x16x32_bf16(pa1, ones, accl, 0, 0, 0);

      __builtin_amdgcn_s_setprio(1);
#pragma unroll
      for (int jf = 0; jf < 8; ++jf) {
        bf16x8 v0 = *(const bf16x8*)(&Vs[p][(jf * 16 + lr) * 64 + ((g ^ (lr & 7)) * 8)]);
        bf16x8 v1 = *(const bf16x8*)(&Vs[p][(jf * 16 + lr) * 64 + (((4 + g) ^ (lr & 7)) * 8)]);
        acc[jf] = __builtin_amdgcn_mfma_f32_16x16x32_bf16(pa0, v0, acc[jf], 0, 0, 0);
        acc[jf] = __builtin_amdgcn_mfma_f32_16x16x32_bf16(pa1, v1, acc[jf], 0, 0, 0);
      }
      __builtin_amdgcn_s_setprio(0);
    }

    BAR_LGKM();
  }
#undef STAGE

  const int h = bh & 15;
  float rl[4];
#pragma unroll
  for (int r = 0; r < 4; ++r) rl[r] = __builtin_amdgcn_rcpf(accl[r]);
#pragma unroll
  for (int jf = 0; jf < 8; ++jf)
#pragma unroll
    for (int r = 0; r < 4; ++r) {
      int tt = qb + w * 16 + g * 4 + r;
      Yg[((size_t)b * 2048 + tt) * 2048 + h * 128 + jf * 16 + lr] = f2bf(acc[jf][r] * rl[r]);
    }
}

// ---------------- launch ----------------
extern "C" void kernel_launch(void* const* d_in, const int* in_sizes, int n_in, void* d_out,
                              int out_size, void* d_ws, size_t ws_size, hipStream_t stream) {
  const float* x = (const float*)d_in[0];
  const unsigned char* amask = (const unsigned char*)d_in[1];
  const int* iscausal = (const int*)d_in[2];
  const float* wqkv = (const float*)d_in[3];
  const float* wout = (const float*)d_in[4];
  float* out = (float*)d_out;

  const size_t MT = 8192, D = 2048, ND = 6144;
  unsigned short* xb = (unsigned short*)d_ws;
  unsigned short* wqkvb = xb + MT * D;
  unsigned short* woutb = wqkvb + ND * D;
  unsigned short* q = woutb + D * D;
  unsigned short* k = q + MT * D;
  unsigned short* vt = k + MT * D;
  unsigned short* y = vt + MT * D;
  float* tab = (float*)(y + MT * D);
  if (ws_size < (size_t)(100663296) * 2 + 2048 * 128 * 4) return;

  cvt3<<<dim3(32768), dim3(256), 0, stream>>>(x, wqkv, wout, xb, wqkvb, woutb);
  rope_table<<<dim3(512), dim3(256), 0, stream>>>(tab);
  gemm256<1><<<dim3(24, 32), dim3(512), 0, stream>>>(xb, wqkvb, nullptr, 8192, 6144, 2048, q, k, vt);
  rope_apply<<<dim3(8192), dim3(256), 0, stream>>>(q, k, tab);
  flash_attn<<<dim3(512), dim3(1024), 0, stream>>>(q, k, vt, y, iscausal, amask);
  gemm256<0><<<dim3(8, 32), dim3(512), 0, stream>>>(y, woutb, out, 8192, 2048, 2048, nullptr,
                                                    nullptr, nullptr);
}

// Round 18
// 439.840 us; speedup vs baseline: 1.2889x; 1.0048x over previous
//
#include <hip/hip_runtime.h>
#include <stdint.h>
#include <stddef.h>

typedef float f32x4 __attribute__((ext_vector_type(4)));
typedef __bf16 bf16x8 __attribute__((ext_vector_type(8)));
typedef short s16x4 __attribute__((ext_vector_type(4)));

#define DEVI static __device__ __forceinline__

DEVI float bf2f(unsigned short u) {
  unsigned int x = ((unsigned int)u) << 16;
  float f;
  __builtin_memcpy(&f, &x, 4);
  return f;
}
DEVI unsigned short f2bf(float f) {
  unsigned int x;
  __builtin_memcpy(&x, &f, 4);
  unsigned int r = (x + 0x7fffu + ((x >> 16) & 1u)) >> 16;
  return (unsigned short)r;
}

DEVI void async16(const void* g, void* l) {
  __builtin_amdgcn_global_load_lds((__attribute__((address_space(1))) void*)g,
                                   (__attribute__((address_space(3))) void*)l,
                                   16, 0, 0);
}

// counted-vmcnt barrier: N loads may stay in flight (T4).
#define BAR_VM(N)                                               \
  do {                                                          \
    asm volatile("s_waitcnt vmcnt(" #N ")" ::: "memory");       \
    __builtin_amdgcn_s_barrier();                               \
    __builtin_amdgcn_sched_barrier(0);                          \
  } while (0)

// raw barrier with own-LDS-ops drain; vmcnt NOT touched.
#define BAR_LGKM()                                          \
  do {                                                      \
    asm volatile("s_waitcnt lgkmcnt(0)" ::: "memory");      \
    __builtin_amdgcn_s_barrier();                           \
    __builtin_amdgcn_sched_barrier(0);                      \
  } while (0)

// ------- fused fp32->bf16 conversion (x, w_qkv, w_out) + RoPE table build -------
__global__ __launch_bounds__(256) void cvt3(const float* __restrict__ x,
                                            const float* __restrict__ wq,
                                            const float* __restrict__ wo,
                                            unsigned short* __restrict__ xb,
                                            unsigned short* __restrict__ wqb,
                                            unsigned short* __restrict__ wob,
                                            float* __restrict__ tab) {
  const int n1 = 16777216, n2 = 12582912, n3 = 4194304;
  int i = (blockIdx.x * 256 + threadIdx.x) * 4;
  if (i >= n1 + n2 + n3) {
    // RoPE table region: one thread per (tt, j)
    int idx = i / 4 - (n1 + n2 + n3) / 4;
    if (idx >= 2048 * 64) return;
    int tt = idx >> 6, j = idx & 63;
    float inv = powf(10000.0f, -(float)j * (1.0f / 64.0f));
    float ang = (float)tt * inv;
    tab[tt * 128 + j] = cosf(ang);
    tab[tt * 128 + 64 + j] = sinf(ang);
    return;
  }
  const float* src;
  unsigned short* dst;
  int off;
  if (i < n1) {
    src = x; dst = xb; off = i;
  } else if (i < n1 + n2) {
    src = wq; dst = wqb; off = i - n1;
  } else {
    src = wo; dst = wob; off = i - n1 - n2;
  }
  float4 v = *(const float4*)(src + off);
  s16x4 o;
  o[0] = (short)f2bf(v.x);
  o[1] = (short)f2bf(v.y);
  o[2] = (short)f2bf(v.z);
  o[3] = (short)f2bf(v.w);
  *(s16x4*)(dst + off) = o;
}

// ---------------- RoPE apply, K ONLY (Q roped in-register inside flash_attn) --------
__global__ __launch_bounds__(256) void rope_apply_k(unsigned short* __restrict__ Kg,
                                                    const float* __restrict__ tab) {
  int idx = blockIdx.x * 256 + threadIdx.x;  // bh*2048*16 + tt*16 + j4
  int j4 = idx & 15;
  int tt = (idx >> 4) & 2047;
  int bh = idx >> 15;
  size_t base = ((size_t)bh * 2048 + tt) * 128;
  f32x4 c4 = *(const f32x4*)(tab + tt * 128 + j4 * 4);
  f32x4 s4 = *(const f32x4*)(tab + tt * 128 + 64 + j4 * 4);
  s16x4 k1 = *(const s16x4*)(Kg + base + j4 * 4);
  s16x4 k2 = *(const s16x4*)(Kg + base + 64 + j4 * 4);
  s16x4 p1, p2;
#pragma unroll
  for (int r = 0; r < 4; ++r) {
    float c = c4[r], s = s4[r];
    float ka = bf2f((unsigned short)k1[r]), kb = bf2f((unsigned short)k2[r]);
    p1[r] = (short)f2bf(ka * c - kb * s);
    p2[r] = (short)f2bf(ka * s + kb * c);
  }
  *(s16x4*)(Kg + base + j4 * 4) = p1;
  *(s16x4*)(Kg + base + 64 + j4 * 4) = p2;
}

// ---------------- 256x256 8-phase GEMM (R15: best measured + rect XCD chunk) ----------
template <int EPI>
__global__ __launch_bounds__(512) void gemm256(const unsigned short* __restrict__ A,
                                               const unsigned short* __restrict__ B,
                                               float* __restrict__ C, int M, int N, int K,
                                               unsigned short* __restrict__ Q,
                                               unsigned short* __restrict__ Kk,
                                               unsigned short* __restrict__ VT) {
  __shared__ __attribute__((aligned(128))) unsigned short Al[2][2][8192];
  __shared__ __attribute__((aligned(128))) unsigned short Bl[2][2][8192];
  const int t = threadIdx.x;
  const int lane = t & 63;
  const int w = t >> 6, wr = w >> 2, wc = w & 3;
  const int g = lane >> 4, lr = lane & 15;

  // balanced rectangular XCD chunking (requires mt%4==0, nt%2==0)
  const int id = blockIdx.y * gridDim.x + blockIdx.x;
  const int mt = M >> 8, nt = N >> 8;
  const int xcd = id & 7;
  const int local = id >> 3;
  const int rm = mt >> 2, rn = nt >> 1;
  const int bm = ((xcd & 3) * rm + (local % rm)) * 256;
  const int bn = ((xcd >> 2) * rn + (local / rm)) * 256;

  const unsigned short* aptr = A + (size_t)bm * K;
  const unsigned short* bptr = B + (size_t)bn * K;

  const int srow = t >> 3;
  const int sslot = (t & 7) ^ (srow & 7);

#define STG(arr, mat, p, h, kt)                                                   \
  do {                                                                            \
    const unsigned short* _s =                                                    \
        (mat) + (size_t)((h) * 128 + srow) * K + (size_t)(kt) * 64 + sslot * 8;   \
    async16(_s, &arr[p][h][t * 8]);                                               \
    async16(_s + (size_t)64 * K, &arr[p][h][t * 8 + 4096]);                       \
  } while (0)

  const int u0 = ((g ^ (lr & 7)) * 8) + lr * 64;
  const int u1 = (((4 + g) ^ (lr & 7)) * 8) + lr * 64;

#define LDA_(p, mh)                                                               \
  _Pragma("unroll") for (int mf = 0; mf < 4; ++mf) {                              \
    af[mf][0] = *(const bf16x8*)&Al[p][wr][(mh) * 4096 + mf * 1024 + u0];         \
    af[mf][1] = *(const bf16x8*)&Al[p][wr][(mh) * 4096 + mf * 1024 + u1];         \
  }
#define LDB_(dst, p, nh)                                                          \
  _Pragma("unroll") for (int nf = 0; nf < 2; ++nf) {                              \
    dst[nf][0] = *(const bf16x8*)&Bl[p][wc >> 1][(wc & 1) * 4096 + (nh) * 2048 +  \
                                                 nf * 1024 + u0];                 \
    dst[nf][1] = *(const bf16x8*)&Bl[p][wc >> 1][(wc & 1) * 4096 + (nh) * 2048 +  \
                                                 nf * 1024 + u1];                 \
  }
#define MMA_(bsrc, mh, nh)                                                        \
  __builtin_amdgcn_s_setprio(1);                                                  \
  _Pragma("unroll") for (int mf = 0; mf < 4; ++mf)                                \
      _Pragma("unroll") for (int nf = 0; nf < 2; ++nf) {                          \
    acc[(mh) * 4 + mf][(nh) * 2 + nf] = __builtin_amdgcn_mfma_f32_16x16x32_bf16(  \
        af[mf][0], bsrc[nf][0], acc[(mh) * 4 + mf][(nh) * 2 + nf], 0, 0, 0);      \
    acc[(mh) * 4 + mf][(nh) * 2 + nf] = __builtin_amdgcn_mfma_f32_16x16x32_bf16(  \
        af[mf][1], bsrc[nf][1], acc[(mh) * 4 + mf][(nh) * 2 + nf], 0, 0, 0);      \
  }                                                                               \
  __builtin_amdgcn_s_setprio(0);
#define BARR() __builtin_amdgcn_s_barrier();

  f32x4 acc[8][4] = {};
  bf16x8 af[4][2], bfrA[2][2], bfrB[2][2];

  STG(Al, aptr, 0, 0, 0);
  STG(Al, aptr, 0, 1, 0);
  STG(Bl, bptr, 0, 0, 0);
  STG(Bl, bptr, 0, 1, 0);
  STG(Bl, bptr, 1, 0, 1);
  STG(Bl, bptr, 1, 1, 1);
  asm volatile("s_waitcnt vmcnt(4)" ::: "memory");
  __builtin_amdgcn_s_barrier();

  const int NITER = K >> 7;
  for (int i = 0; i < NITER; ++i) {
    const bool G = (i + 1 < NITER);
    const int t1 = 2 * i + 1, t2 = 2 * i + 2, t3 = 2 * i + 3;

    LDA_(0, 0);
    LDB_(bfrA, 0, 0);
    STG(Al, aptr, 1, 0, t1);
    STG(Al, aptr, 1, 1, t1);
    BARR();
    MMA_(bfrA, 0, 0);
    BARR();
    LDB_(bfrB, 0, 1);
    BARR();
    MMA_(bfrB, 0, 1);
    BARR();
    LDA_(0, 1);
    BARR();
    MMA_(bfrB, 1, 1);
    BARR();
    if (G) {
      STG(Bl, bptr, 0, 0, t2);
      asm volatile("s_waitcnt vmcnt(2)" ::: "memory");
    } else {
      asm volatile("s_waitcnt vmcnt(0)" ::: "memory");
    }
    BARR();
    MMA_(bfrA, 1, 0);
    BARR();
    LDA_(1, 0);
    LDB_(bfrA, 1, 0);
    if (G) STG(Bl, bptr, 0, 1, t2);
    BARR();
    MMA_(bfrA, 0, 0);
    BARR();
    LDB_(bfrB, 1, 1);
    if (G) STG(Al, aptr, 0, 0, t2);
    BARR();
    MMA_(bfrB, 0, 1);
    BARR();
    LDA_(1, 1);
    if (G) STG(Al, aptr, 0, 1, t2);
    BARR();
    MMA_(bfrB, 1, 1);
    BARR();
    if (G) {
      STG(Bl, bptr, 1, 0, t3);
      STG(Bl, bptr, 1, 1, t3);
      asm volatile("s_waitcnt vmcnt(4)" ::: "memory");
    }
    BARR();
    MMA_(bfrA, 1, 0);
    BARR();
  }
#undef STG
#undef LDA_
#undef LDB_
#undef MMA_
#undef BARR

  if (EPI == 0) {
#pragma unroll
    for (int mp = 0; mp < 8; ++mp) {
      int m0 = bm + wr * 128 + (mp >> 2) * 64 + (mp & 3) * 16 + g * 4;
#pragma unroll
      for (int nfi = 0; nfi < 4; ++nfi) {
        int n = bn + wc * 64 + (nfi >> 1) * 32 + (nfi & 1) * 16 + lr;
#pragma unroll
        for (int r = 0; r < 4; ++r) C[(size_t)(m0 + r) * N + n] = acc[mp][nfi][r];
      }
    }
  } else {
    const int bi = bm >> 11;
    const int tbase = bm & 2047;
#pragma unroll
    for (int nfi = 0; nfi < 4; ++nfi) {
      int e = bn + wc * 64 + (nfi >> 1) * 32 + (nfi & 1) * 16 + lr;
      int region = e >> 11;
      int e2 = e & 2047;
      int h = e2 >> 7, d = e2 & 127;
      int bh = bi * 16 + h;
#pragma unroll
      for (int mp = 0; mp < 8; ++mp) {
        int trow = tbase + wr * 128 + (mp >> 2) * 64 + (mp & 3) * 16 + g * 4;
        if (region == 2) {
          s16x4 pk;
#pragma unroll
          for (int r = 0; r < 4; ++r) pk[r] = (short)f2bf(acc[mp][nfi][r]);
          *(s16x4*)(VT + ((size_t)bh * 128 + d) * 2048 + trow) = pk;
        } else {
          unsigned short* dst = (region == 0) ? Q : Kk;
#pragma unroll
          for (int r = 0; r < 4; ++r)
            dst[((size_t)bh * 2048 + trow + r) * 128 + d] = f2bf(acc[mp][nfi][r]);
        }
      }
    }
  }
}

// ---------------- flash attention: QBLK=256, 1024 thr = 16 waves ----------------
// R18: Q-RoPE applied IN-REGISTER at block start (partners d<->d+64 are
// qf[0]<->qf[2], qf[1]<->qf[3] within the same thread; ~200 VALU once per
// block). Q in workspace is now RAW (gemm epilogue unchanged); scale*log2e
// applied here. Rest identical to R17 (verified).
__global__ __launch_bounds__(1024) void flash_attn(const unsigned short* __restrict__ Qg,
                                                   const unsigned short* __restrict__ Kg,
                                                   const unsigned short* __restrict__ VTg,
                                                   unsigned short* __restrict__ Yg,
                                                   const int* __restrict__ iscausal,
                                                   const unsigned char* __restrict__ amask,
                                                   const float* __restrict__ tab) {
  __shared__ __attribute__((aligned(128))) unsigned short Ks[2][64 * 128];
  __shared__ __attribute__((aligned(128))) unsigned short Vs[2][128 * 64];
  __shared__ __attribute__((aligned(128))) unsigned short Ps[16][16 * 72];

  const int t = threadIdx.x, lane = t & 63, w = t >> 6;  // w 0..15
  const int g = lane >> 4, lr = lane & 15;
  const int id = blockIdx.x;
  const int xcd = id & 7, j5 = id >> 3;  // j5 0..63
  const int rr = j5 >> 3;                // round 0..7
  const int qbi = (rr & 1) ? (rr >> 1) : (7 - (rr >> 1));  // {7,0,6,1,5,2,4,3}
  const int bh = xcd * 8 + (j5 & 7);
  const int b = bh >> 4;
  const int qb = qbi * 256;
  const int causal = iscausal[0] != 0;
  const int nt = causal ? (4 * qbi + 4) : 32;

  // load raw Q, apply RoPE + scale*log2e in-register
  const float S2 = 0.0883883476483184f * 1.44269504088896341f;
  const int qpos = qb + w * 16 + lr;
  const unsigned short* qrow = Qg + ((size_t)bh * 2048 + qpos) * 128;
  const float* trow = tab + (size_t)qpos * 128;
  bf16x8 qraw[4];
#pragma unroll
  for (int ds = 0; ds < 4; ++ds) qraw[ds] = *(const bf16x8*)(qrow + ds * 32 + g * 8);
  bf16x8 qf[4];
  {
    unsigned short* tq = (unsigned short*)qraw;
    unsigned short* oq = (unsigned short*)qf;
#pragma unroll
    for (int half = 0; half < 2; ++half)
#pragma unroll
      for (int e = 0; e < 8; ++e) {
        int j = half * 32 + g * 8 + e;
        float c = trow[j], s = trow[64 + j];
        float a = bf2f(tq[half * 8 + e]);
        float b2 = bf2f(tq[(half + 2) * 8 + e]);
        oq[half * 8 + e] = f2bf((a * c - b2 * s) * S2);
        oq[(half + 2) * 8 + e] = f2bf((a * s + b2 * c) * S2);
      }
  }

  const unsigned short* Kbase = Kg + (size_t)bh * 2048 * 128;
  const unsigned short* Vbase = VTg + (size_t)bh * 128 * 2048;

  const int rK = t >> 4, sK = (t & 15) ^ (rK & 15);
  const int rV = t >> 3, sV = (t & 7) ^ (rV & 7);

#define STAGE(KT, P)                                                              \
  do {                                                                            \
    const int _kv = (KT) * 64;                                                    \
    async16(Kbase + (size_t)(_kv + rK) * 128 + sK * 8, &Ks[P][t * 8]);            \
    async16(Vbase + (size_t)rV * 2048 + _kv + sV * 8, &Vs[P][t * 8]);             \
  } while (0)

  unsigned int oi[4] = {0x3F803F80u, 0x3F803F80u, 0x3F803F80u, 0x3F803F80u};
  bf16x8 ones;
  __builtin_memcpy(&ones, oi, 16);

  f32x4 acc[8] = {};
  f32x4 accl = {0.f, 0.f, 0.f, 0.f};
  float mrow[4] = {-1e30f, -1e30f, -1e30f, -1e30f};

  STAGE(0, 0);

  for (int kt = 0; kt < nt; ++kt) {
    const int p = kt & 1;
    const int kv0 = kt * 64;
    if (kt + 1 < nt) {
      STAGE(kt + 1, p ^ 1);
      BAR_VM(2);
    } else {
      BAR_VM(0);
    }

    const int qw = qb + w * 16;
    const bool active = !causal || (kv0 <= qw + 15);  // wave-uniform
    if (active) {
      f32x4 s[4] = {};
      __builtin_amdgcn_s_setprio(1);
#pragma unroll
      for (int cf = 0; cf < 4; ++cf)
#pragma unroll
        for (int ds = 0; ds < 4; ++ds) {
          bf16x8 kf = *(const bf16x8*)(&Ks[p][(cf * 16 + lr) * 128 + (((ds * 4 + g) ^ lr) * 8)]);
          s[cf] = __builtin_amdgcn_mfma_f32_16x16x32_bf16(qf[ds], kf, s[cf], 0, 0, 0);
        }
      __builtin_amdgcn_s_setprio(0);

      const int q0 = qw + g * 4;
      if (causal) {
        if (kv0 + 63 > qw) {
#pragma unroll
          for (int cf = 0; cf < 4; ++cf) {
            int kvg = kv0 + cf * 16 + lr;
#pragma unroll
            for (int r = 0; r < 4; ++r)
              if (kvg > q0 + r) s[cf][r] = -1e30f;
          }
        }
      } else {
#pragma unroll
        for (int cf = 0; cf < 4; ++cf) {
          int kvg = kv0 + cf * 16 + lr;
          if (!amask[(size_t)b * 2048 + kvg]) {
#pragma unroll
            for (int r = 0; r < 4; ++r) s[cf][r] = -1e30f;
          }
        }
      }

      f32x4 lm;
#pragma unroll
      for (int r = 0; r < 4; ++r)
        lm[r] = fmaxf(fmaxf(s[0][r], s[1][r]), fmaxf(s[2][r], s[3][r]));
      bool ok = true;
#pragma unroll
      for (int r = 0; r < 4; ++r) ok = ok && (lm[r] <= mrow[r] + 8.0f);
      if (!__all(ok)) {
        f32x4 mx = lm;
#pragma unroll
        for (int off = 8; off >= 1; off >>= 1)
#pragma unroll
          for (int r = 0; r < 4; ++r) mx[r] = fmaxf(mx[r], __shfl_xor(mx[r], off));
#pragma unroll
        for (int r = 0; r < 4; ++r) {
          float mn = fmaxf(mrow[r], mx[r]);
          float corr = exp2f(mrow[r] - mn);
          mrow[r] = mn;
          accl[r] *= corr;
#pragma unroll
          for (int jf = 0; jf < 8; ++jf) acc[jf][r] *= corr;
        }
      }

#pragma unroll
      for (int cf = 0; cf < 4; ++cf)
#pragma unroll
        for (int r = 0; r < 4; ++r) s[cf][r] = exp2f(s[cf][r] - mrow[r]);

      unsigned short* Pw = &Ps[w][0];
#pragma unroll
      for (int cf = 0; cf < 4; ++cf)
#pragma unroll
        for (int r = 0; r < 4; ++r) Pw[(g * 4 + r) * 72 + cf * 16 + lr] = f2bf(s[cf][r]);
      asm volatile("s_waitcnt lgkmcnt(0)" ::: "memory");
      __builtin_amdgcn_sched_barrier(0);

      bf16x8 pa0 = *(const bf16x8*)(Pw + lr * 72 + g * 8);
      bf16x8 pa1 = *(const bf16x8*)(Pw + lr * 72 + 32 + g * 8);

      accl = __builtin_amdgcn_mfma_f32_16x16x32_bf16(pa0, ones, accl, 0, 0, 0);
      accl = __builtin_amdgcn_mfma_f32_16x16x32_bf16(pa1, ones, accl, 0, 0, 0);

      __builtin_amdgcn_s_setprio(1);
#pragma unroll
      for (int jf = 0; jf < 8; ++jf) {
        bf16x8 v0 = *(const bf16x8*)(&Vs[p][(jf * 16 + lr) * 64 + ((g ^ (lr & 7)) * 8)]);
        bf16x8 v1 = *(const bf16x8*)(&Vs[p][(jf * 16 + lr) * 64 + (((4 + g) ^ (lr & 7)) * 8)]);
        acc[jf] = __builtin_amdgcn_mfma_f32_16x16x32_bf16(pa0, v0, acc[jf], 0, 0, 0);
        acc[jf] = __builtin_amdgcn_mfma_f32_16x16x32_bf16(pa1, v1, acc[jf], 0, 0, 0);
      }
      __builtin_amdgcn_s_setprio(0);
    }

    BAR_LGKM();
  }
#undef STAGE

  const int h = bh & 15;
  float rl[4];
#pragma unroll
  for (int r = 0; r < 4; ++r) rl[r] = __builtin_amdgcn_rcpf(accl[r]);
#pragma unroll
  for (int jf = 0; jf < 8; ++jf)
#pragma unroll
    for (int r = 0; r < 4; ++r) {
      int tt = qb + w * 16 + g * 4 + r;
      Yg[((size_t)b * 2048 + tt) * 2048 + h * 128 + jf * 16 + lr] = f2bf(acc[jf][r] * rl[r]);
    }
}

// ---------------- launch ----------------
extern "C" void kernel_launch(void* const* d_in, const int* in_sizes, int n_in, void* d_out,
                              int out_size, void* d_ws, size_t ws_size, hipStream_t stream) {
  const float* x = (const float*)d_in[0];
  const unsigned char* amask = (const unsigned char*)d_in[1];
  const int* iscausal = (const int*)d_in[2];
  const float* wqkv = (const float*)d_in[3];
  const float* wout = (const float*)d_in[4];
  float* out = (float*)d_out;

  const size_t MT = 8192, D = 2048, ND = 6144;
  unsigned short* xb = (unsigned short*)d_ws;
  unsigned short* wqkvb = xb + MT * D;
  unsigned short* woutb = wqkvb + ND * D;
  unsigned short* q = woutb + D * D;
  unsigned short* k = q + MT * D;
  unsigned short* vt = k + MT * D;
  unsigned short* y = vt + MT * D;
  float* tab = (float*)(y + MT * D);
  if (ws_size < (size_t)(100663296) * 2 + 2048 * 128 * 4) return;

  // cvt3 grid: 33.5M elems / 1024 per block = 32768 + 512 blocks of table work
  cvt3<<<dim3(33280), dim3(256), 0, stream>>>(x, wqkv, wout, xb, wqkvb, woutb, tab);
  gemm256<1><<<dim3(24, 32), dim3(512), 0, stream>>>(xb, wqkvb, nullptr, 8192, 6144, 2048, q, k, vt);
  rope_apply_k<<<dim3(8192), dim3(256), 0, stream>>>(k, tab);
  flash_attn<<<dim3(512), dim3(1024), 0, stream>>>(q, k, vt, y, iscausal, amask, tab);
  gemm256<0><<<dim3(8, 32), dim3(512), 0, stream>>>(y, woutb, out, 8192, 2048, 2048, nullptr,
                                                    nullptr, nullptr);
}